// Round 7
// baseline (349.909 us; speedup 1.0000x reference)
//
#include <hip/hip_runtime.h>
#include <hip/hip_bf16.h>
#include <stdint.h>

#define N_NODES 100000
#define N_EDGES 1600000
#define N_GRAPHS 64
#define HDIM 128

#define BUCKET_SHIFT 9
#define NBUCK ((N_NODES + 511) >> 9)                  // 196
#define CAP 9728                                      // real edges (mean 8192 + 11 sigma) + 512 self entries
#define SCAT_CHUNK 8192
#define SCAT_NBLK ((N_EDGES + SCAT_CHUNK - 1) / SCAT_CHUNK)  // 196
#define GB_NBLK ((N_NODES + 255) / 256)               // 391

typedef __bf16 bf16x8 __attribute__((ext_vector_type(8)));
typedef float f32x4 __attribute__((ext_vector_type(4)));
typedef float f32x2 __attribute__((ext_vector_type(2)));

// ---------------- fused setup: graph_bounds | transpose W1/W2 | init gcur/psum ----------------
__global__ __launch_bounds__(256) void setup_kernel(const int* __restrict__ batch,
                                                    int* __restrict__ gstart,
                                                    const float* __restrict__ W1,
                                                    const float* __restrict__ W2,
                                                    __hip_bfloat16* __restrict__ Wt1,
                                                    __hip_bfloat16* __restrict__ Wt2,
                                                    int* __restrict__ gcur,
                                                    float* __restrict__ psum) {
    int bid = blockIdx.x;
    if (bid < GB_NBLK) {
        int i = bid * 256 + threadIdx.x;
        if (i >= N_NODES) return;
        int b = batch[i];
        int prev = (i == 0) ? -1 : batch[i - 1];
        for (int g = prev + 1; g <= b; ++g) gstart[g] = i;
        if (i == N_NODES - 1) {
            for (int g = b + 1; g <= N_GRAPHS; ++g) gstart[g] = N_NODES;
        }
    } else if (bid < GB_NBLK + 128) {
        int t = bid - GB_NBLK;
        const float* W = (t < 64) ? W1 : W2;
        __hip_bfloat16* Wt = (t < 64) ? Wt1 : Wt2;
        int bb = t & 63;
        int n = bb * 2 + (threadIdx.x >> 7);
        int k = threadIdx.x & 127;
        Wt[n * 128 + k] = __float2bfloat16(W[k * 128 + n]);
    } else {
        int i = (bid - GB_NBLK - 128) * 256 + threadIdx.x;
        if (i < NBUCK) gcur[i] = i * CAP;
        int j = i - NBUCK;
        if (j >= 0 && j < N_GRAPHS * HDIM) psum[j] = 0.f;
    }
}
#define SETUP_NBLK (GB_NBLK + 128 + (NBUCK + N_GRAPHS * HDIM + 255) / 256)

// ---------------- scatter edges into capacity-strided buckets ----------------
// packed entry: (local_dst << 17) | src   (src < 2^17, local_dst < 512)
__global__ __launch_bounds__(256) void scatter_kernel(const int* __restrict__ src,
                                                      const int* __restrict__ dst,
                                                      int* __restrict__ gcur,
                                                      int* __restrict__ sorted, int E) {
    __shared__ int hist[NBUCK];
    __shared__ int base_s[NBUCK];
    int tid = threadIdx.x;
    int e0 = blockIdx.x * SCAT_CHUNK;
    int sv[SCAT_CHUNK / 256], dv[SCAT_CHUNK / 256];
#pragma unroll
    for (int j = 0; j < SCAT_CHUNK / 256; j++) {
        int e = e0 + (j << 8) + tid;
        if (e < E) { sv[j] = src[e]; dv[j] = dst[e]; } else { sv[j] = -1; dv[j] = -1; }
    }
    if (tid < NBUCK) hist[tid] = 0;
    __syncthreads();
#pragma unroll
    for (int j = 0; j < SCAT_CHUNK / 256; j++)
        if (dv[j] >= 0) atomicAdd(&hist[dv[j] >> BUCKET_SHIFT], 1);
    __syncthreads();
    if (tid < NBUCK) {
        int c = hist[tid];
        base_s[tid] = (c > 0) ? atomicAdd(&gcur[tid], c) : 0;
    }
    __syncthreads();
    if (tid < NBUCK) hist[tid] = 0;
    __syncthreads();
#pragma unroll
    for (int j = 0; j < SCAT_CHUNK / 256; j++) {
        if (dv[j] >= 0) {
            int b = dv[j] >> BUCKET_SHIFT;
            int idx = atomicAdd(&hist[b], 1);
            sorted[base_s[b] + idx] = ((dv[j] & 511) << 17) | sv[j];
        }
    }
}

// ---------------- per-bucket: degree, dis, row (start,end), CSR fill — LDS-staged ----------------
// Appends one self-loop entry per node at the end of its segment.
__global__ __launch_bounds__(256) void bucket_build_kernel(const int* __restrict__ sorted,
                                                           const int* __restrict__ gcur,
                                                           int2* __restrict__ rs2,
                                                           float* __restrict__ dis,
                                                           int* __restrict__ csr_src) {
    __shared__ int edges[CAP];     // 38 KB — bucket's edge list staged once
    __shared__ int cnt[512];
    __shared__ int excl[512];
    __shared__ int ps[256];
    int b = blockIdx.x, tid = threadIdx.x;
    cnt[tid] = 0; cnt[tid + 256] = 0;
    int node0 = b << BUCKET_SHIFT;
    int lo = b * CAP, hi = gcur[b];
    int ne = hi - lo;
    for (int i = tid; i < ne; i += 256) edges[i] = sorted[lo + i];
    __syncthreads();
    for (int i = tid; i < ne; i += 256)
        atomicAdd(&cnt[((unsigned)edges[i]) >> 17], 1);
    __syncthreads();
    // pair-scan of 512 counts with 256 threads
    int c0 = cnt[2 * tid], c1 = cnt[2 * tid + 1];
    ps[tid] = c0 + c1;
    __syncthreads();
#pragma unroll
    for (int off = 1; off < 256; off <<= 1) {
        int t = (tid >= off) ? ps[tid - off] : 0;
        __syncthreads();
        ps[tid] += t;
        __syncthreads();
    }
    int pex = ps[tid] - (c0 + c1);
    excl[2 * tid] = pex;
    excl[2 * tid + 1] = pex + c0;
    __syncthreads();
#pragma unroll
    for (int k = 0; k < 2; k++) {
        int li = tid + k * 256;
        int node = node0 + li;
        if (node < N_NODES) {
            // segment start shifted by li to make room for earlier nodes' self entries
            int st = lo + excl[li] + li;
            int c = cnt[li];
            rs2[node] = make_int2(st, st + c + 1);      // +1: self entry included
            dis[node] = rsqrtf((float)c + 1.0f);
            csr_src[st + c] = node;                     // self-loop entry (global id)
        }
    }
    // reuse cnt as fill cursors
    cnt[tid] = 0; cnt[tid + 256] = 0;
    __syncthreads();
    for (int i = tid; i < ne; i += 256) {
        int v = edges[i];
        int li = ((unsigned)v) >> 17;
        int idx = atomicAdd(&cnt[li], 1);
        csr_src[lo + excl[li] + li + idx] = v & 0x1FFFF;
    }
}

// ---------------- MFMA GEMM: C_fp8[r][c] = e4m3( (sum_k A[r][k] W[k][c]) * scale[r] )
template<bool A_FP32>
__global__ __launch_bounds__(256) void gemm_mfma_kernel(const void* __restrict__ Av,
                                                        const __hip_bfloat16* __restrict__ Wt,
                                                        const float* __restrict__ scale,
                                                        unsigned char* __restrict__ C, int nrows) {
    __shared__ float Cs[64 * 132];
    int tid = threadIdx.x;
    int wave = tid >> 6, lane = tid & 63;
    int quad = lane >> 4, l16 = lane & 15;
    int row0 = blockIdx.x * 64;
    int arow = row0 + wave * 16 + l16;
    int arow_c = min(arow, nrows - 1);

    const __hip_bfloat16* A16 = (const __hip_bfloat16*)Av;
    const float* A32 = (const float*)Av;

    f32x4 acc[8];
#pragma unroll
    for (int t = 0; t < 8; t++) acc[t] = (f32x4){0.f, 0.f, 0.f, 0.f};

#pragma unroll
    for (int kt = 0; kt < 4; kt++) {
        int kbase = kt * 32 + quad * 8;
        union { bf16x8 v; __hip_bfloat16 h[8]; uint4 u; } au;
        if (A_FP32) {
            const float* ap = A32 + (size_t)arow_c * 128 + kbase;
            float4 u0 = *(const float4*)ap;
            float4 u1 = *(const float4*)(ap + 4);
            au.h[0] = __float2bfloat16(u0.x); au.h[1] = __float2bfloat16(u0.y);
            au.h[2] = __float2bfloat16(u0.z); au.h[3] = __float2bfloat16(u0.w);
            au.h[4] = __float2bfloat16(u1.x); au.h[5] = __float2bfloat16(u1.y);
            au.h[6] = __float2bfloat16(u1.z); au.h[7] = __float2bfloat16(u1.w);
        } else {
            au.u = *(const uint4*)(A16 + (size_t)arow_c * 128 + kbase);
        }
#pragma unroll
        for (int t = 0; t < 8; t++) {
            bf16x8 b = *(const bf16x8*)(Wt + (size_t)(t * 16 + l16) * 128 + kbase);
            acc[t] = __builtin_amdgcn_mfma_f32_16x16x32_bf16(au.v, b, acc[t], 0, 0, 0);
        }
    }

    int rbase = wave * 16 + quad * 4;
    float s[4];
#pragma unroll
    for (int r = 0; r < 4; r++) s[r] = scale[min(row0 + rbase + r, nrows - 1)];
#pragma unroll
    for (int t = 0; t < 8; t++) {
#pragma unroll
        for (int r = 0; r < 4; r++)
            Cs[(rbase + r) * 132 + t * 16 + l16] = acc[t][r] * s[r];
    }
    __syncthreads();

#pragma unroll
    for (int p = 0; p < 4; p++) {
        int g = p * 256 + tid;
        int row = g >> 4, c8 = (g & 15) * 8;
        int grow = row0 + row;
        if (grow < nrows) {
            const float* cp = &Cs[row * 132 + c8];
            float4 v0 = *(const float4*)cp;
            float4 v1 = *(const float4*)(cp + 4);
            int w0 = __builtin_amdgcn_cvt_pk_fp8_f32(v0.x, v0.y, 0, false);
            w0 = __builtin_amdgcn_cvt_pk_fp8_f32(v0.z, v0.w, w0, true);
            int w1 = __builtin_amdgcn_cvt_pk_fp8_f32(v1.x, v1.y, 0, false);
            w1 = __builtin_amdgcn_cvt_pk_fp8_f32(v1.z, v1.w, w1, true);
            *(uint2*)(C + (size_t)grow * 128 + c8) = make_uint2((unsigned)w0, (unsigned)w1);
        }
    }
}

// ---------------- GCN aggregation (R16 structure): 2 nodes/wave, uint2 gathers, 8 gathers/round,
// masked single-round tail, 32-bit addressing.
// FUSE_POOL: skip abuf store; accumulate post-ReLU f32 into psum (global_mean_pool numerator)
// via per-block 128-float LDS accumulator + 1 global atomic per feature per block. ----------------
__device__ __forceinline__ void accum8p(f32x2* acc, uint2 u) {
    acc[0] += __builtin_amdgcn_cvt_pk_f32_fp8((int)u.x, false);
    acc[1] += __builtin_amdgcn_cvt_pk_f32_fp8((int)u.x, true);
    acc[2] += __builtin_amdgcn_cvt_pk_f32_fp8((int)u.y, false);
    acc[3] += __builtin_amdgcn_cvt_pk_f32_fp8((int)u.y, true);
}

template<bool FUSE_POOL>
__global__ __launch_bounds__(256, 8) void agg_kernel(const unsigned char* __restrict__ h8,
                                                     const float* __restrict__ dis,
                                                     const int2* __restrict__ rs2,
                                                     const int* __restrict__ csr_src,
                                                     const float* __restrict__ bias,
                                                     __hip_bfloat16* __restrict__ out,
                                                     const int* __restrict__ batch,
                                                     float* __restrict__ psum, int n) {
    __shared__ float psum_s[128];
    int tid = threadIdx.x;
    int wid = tid >> 6;
    int lane = tid & 63;
    int half = lane >> 5;          // 0: node A, 1: node B
    int q = lane >> 4;             // quarter 0..3
    int f = lane & 15;
    int l32 = lane & 31;
    int sub = q & 1;               // which of the 2 edges in this gather slot
    int hb = half << 5;            // shfl base for this half's csr chunk
    unsigned fo = (unsigned)(f * 8);
    int blk0 = (int)blockIdx.x * 8;          // first node of this block (int!)

    if (FUSE_POOL) {
        if (tid < 128) psum_s[tid] = 0.f;
        __syncthreads();
    }

    int nodeA = blk0 + wid * 2;
    bool active = nodeA < n;       // grid is exactly full at n=100000; guard kept for safety
    if (!FUSE_POOL && !active) return;
    int nodeB = nodeA + 1;
    bool hasB = nodeB < n;
    int myNode = half ? (hasB ? nodeB : nodeA) : nodeA;
    myNode = min(myNode, n - 1);

    int2 se = rs2[myNode];
    int i0 = se.x;
    int deg = se.y - se.x;         // includes self entry (>= 1)
    if ((half && !hasB) || !active) deg = 0;
    float dn = dis[myNode];

    f32x2 acc[4];
#pragma unroll
    for (int j = 0; j < 4; j++) acc[j] = (f32x2){0.f, 0.f};

    for (int base = 0; base < deg; base += 32) {
        int cnt = min(deg - base, 32);              // uniform within half
        int idx = csr_src[i0 + base + min(l32, cnt - 1)];
        int e = 0;
        // main: 16 edges per half per round, 8 independent uint2 gathers in flight
        for (; e + 16 <= cnt; e += 16) {
            int s0 = __shfl(idx, hb + e + sub, 64);
            int s1 = __shfl(idx, hb + e + 2 + sub, 64);
            int s2 = __shfl(idx, hb + e + 4 + sub, 64);
            int s3 = __shfl(idx, hb + e + 6 + sub, 64);
            int s4 = __shfl(idx, hb + e + 8 + sub, 64);
            int s5 = __shfl(idx, hb + e + 10 + sub, 64);
            int s6 = __shfl(idx, hb + e + 12 + sub, 64);
            int s7 = __shfl(idx, hb + e + 14 + sub, 64);
            uint2 u0 = *(const uint2*)(h8 + (unsigned)(s0 << 7) + fo);
            uint2 u1 = *(const uint2*)(h8 + (unsigned)(s1 << 7) + fo);
            uint2 u2 = *(const uint2*)(h8 + (unsigned)(s2 << 7) + fo);
            uint2 u3 = *(const uint2*)(h8 + (unsigned)(s3 << 7) + fo);
            uint2 u4 = *(const uint2*)(h8 + (unsigned)(s4 << 7) + fo);
            uint2 u5 = *(const uint2*)(h8 + (unsigned)(s5 << 7) + fo);
            uint2 u6 = *(const uint2*)(h8 + (unsigned)(s6 << 7) + fo);
            uint2 u7 = *(const uint2*)(h8 + (unsigned)(s7 << 7) + fo);
            accum8p(acc, u0);
            accum8p(acc, u1);
            accum8p(acc, u2);
            accum8p(acc, u3);
            accum8p(acc, u4);
            accum8p(acc, u5);
            accum8p(acc, u6);
            accum8p(acc, u7);
        }
        // tail: ONE masked round of 8 gathers covering edges e..e+15
        // (clamped index; invalid lanes zero their fp8 payload — 0x00 decodes to 0.0)
        if (e < cnt) {
            int r = cnt - 1;
#pragma unroll
            for (int k = 0; k < 8; k++) {
                int ln = e + 2 * k + sub;
                int s = __shfl(idx, hb + min(ln, r), 64);
                uint2 u = *(const uint2*)(h8 + (unsigned)(s << 7) + fo);
                if (ln > r) { u.x = 0u; u.y = 0u; }
                accum8p(acc, u);
            }
        }
    }

    // combine gather-slot pairs: Q0 += Q1 (node A), Q2 += Q3 (node B)
#pragma unroll
    for (int j = 0; j < 4; j++) {
        f32x2 v = acc[j];
        v[0] += __shfl_down(v[0], 16, 64);
        v[1] += __shfl_down(v[1], 16, 64);
        acc[j] = v;
    }

    bool res = active && (sub == 0) && (half == 0 || hasB);

    if (FUSE_POOL) {
        float rv[8];
        if (res) {
            float4 b0 = *(const float4*)(bias + f * 8);
            float4 b1 = *(const float4*)(bias + f * 8 + 4);
            float bb[8] = {b0.x, b0.y, b0.z, b0.w, b1.x, b1.y, b1.z, b1.w};
#pragma unroll
            for (int k = 0; k < 4; k++) {
                rv[2 * k]     = fmaxf(fmaf(acc[k][0], dn, bb[2 * k]), 0.f);
                rv[2 * k + 1] = fmaxf(fmaf(acc[k][1], dn, bb[2 * k + 1]), 0.f);
            }
        }
        int gA = batch[min(blk0, n - 1)];
        int gB = batch[min(blk0 + 7, n - 1)];
        if (gA == gB) {            // block-uniform branch (typical: batch sorted, 8-node blocks)
            if (res) {
#pragma unroll
                for (int k = 0; k < 8; k++) atomicAdd(&psum_s[f * 8 + k], rv[k]);
            }
            __syncthreads();
            if (tid < 128) {
                float v = psum_s[tid];
                if (v != 0.f) atomicAdd(&psum[gA * 128 + tid], v);
            }
        } else {                   // graph boundary inside block (rare): per-node direct atomics
            if (res) {
                int g = batch[myNode];
#pragma unroll
                for (int k = 0; k < 8; k++) atomicAdd(&psum[g * 128 + f * 8 + k], rv[k]);
            }
        }
    } else {
        if (res) {
            float4 b0 = *(const float4*)(bias + f * 8);
            float4 b1 = *(const float4*)(bias + f * 8 + 4);
            float r0 = fmaxf(fmaf(acc[0][0], dn, b0.x), 0.f);
            float r1 = fmaxf(fmaf(acc[0][1], dn, b0.y), 0.f);
            float r2 = fmaxf(fmaf(acc[1][0], dn, b0.z), 0.f);
            float r3 = fmaxf(fmaf(acc[1][1], dn, b0.w), 0.f);
            float r4 = fmaxf(fmaf(acc[2][0], dn, b1.x), 0.f);
            float r5 = fmaxf(fmaf(acc[2][1], dn, b1.y), 0.f);
            float r6 = fmaxf(fmaf(acc[3][0], dn, b1.z), 0.f);
            float r7 = fmaxf(fmaf(acc[3][1], dn, b1.w), 0.f);
            __hip_bfloat162 p0 = __float22bfloat162_rn(make_float2(r0, r1));
            __hip_bfloat162 p1 = __float22bfloat162_rn(make_float2(r2, r3));
            __hip_bfloat162 p2 = __float22bfloat162_rn(make_float2(r4, r5));
            __hip_bfloat162 p3 = __float22bfloat162_rn(make_float2(r6, r7));
            uint4 pk;
            pk.x = *(unsigned int*)&p0; pk.y = *(unsigned int*)&p1;
            pk.z = *(unsigned int*)&p2; pk.w = *(unsigned int*)&p3;
            *(uint4*)(out + (size_t)myNode * 128 + f * 8) = pk;
        }
    }
}

// ---------------- fused final MLP ----------------
__global__ __launch_bounds__(256) void mlp_kernel(const float* __restrict__ psum,
                                                  const int* __restrict__ gstart,
                                                  const float* __restrict__ sv,
                                                  const float* __restrict__ act,
                                                  const float* __restrict__ Wf1,
                                                  const float* __restrict__ bf1,
                                                  const float* __restrict__ Wf2,
                                                  const float* __restrict__ bf2,
                                                  const float* __restrict__ Wo,
                                                  const float* __restrict__ bo,
                                                  float* __restrict__ out) {
    int g = blockIdx.x, tid = threadIdx.x;
    __shared__ float z[224];
    __shared__ float z1[256];
    __shared__ float red[256];
    if (tid < 128) {
        int c = gstart[g + 1] - gstart[g];
        float cnt = fmaxf((float)c, 1.f);
        z[tid] = psum[g * 128 + tid] / cnt;
    } else if (tid < 192) {
        z[tid] = sv[g * 64 + (tid - 128)];
    } else if (tid < 224) {
        z[tid] = act[g * 32 + (tid - 192)];
    }
    __syncthreads();
    float a = bf1[tid];
    for (int k = 0; k < 224; k++) a = fmaf(z[k], Wf1[k * 256 + tid], a);
    z1[tid] = fmaxf(a, 0.f);
    __syncthreads();
    float b = bf2[tid];
    for (int k = 0; k < 256; k++) b = fmaf(z1[k], Wf2[k * 256 + tid], b);
    b = fmaxf(b, 0.f);
    red[tid] = b * Wo[tid];
    __syncthreads();
    for (int off = 128; off > 0; off >>= 1) {
        if (tid < off) red[tid] += red[tid + off];
        __syncthreads();
    }
    if (tid == 0) out[g] = red[0] + bo[0];
}

// ---------------- launch ----------------
extern "C" void kernel_launch(void* const* d_in, const int* in_sizes, int n_in,
                              void* d_out, int out_size, void* d_ws, size_t ws_size,
                              hipStream_t stream) {
    const float* x   = (const float*)d_in[0];
    const int*   eidx = (const int*)d_in[1];
    const int*   batch = (const int*)d_in[2];
    const float* sv  = (const float*)d_in[3];
    const float* act = (const float*)d_in[4];
    const float* W1  = (const float*)d_in[5];
    const float* b1  = (const float*)d_in[6];
    const float* W2  = (const float*)d_in[7];
    const float* b2  = (const float*)d_in[8];
    const float* Wf1 = (const float*)d_in[9];
    const float* bf1 = (const float*)d_in[10];
    const float* Wf2 = (const float*)d_in[11];
    const float* bf2 = (const float*)d_in[12];
    const float* Wo  = (const float*)d_in[13];
    const float* bo  = (const float*)d_in[14];
    float* out = (float*)d_out;

    const int* srcp = eidx;             // edge_index[0]
    const int* dstp = eidx + N_EDGES;   // edge_index[1]

    char* w = (char*)d_ws;
    int* gcur = (int*)w;               w += (size_t)NBUCK * 4;
    float* psum = (float*)w;           w += (size_t)N_GRAPHS * HDIM * 4;
    int2* rs2 = (int2*)w;              w += (size_t)N_NODES * 8;
    float* dis = (float*)w;            w += (size_t)N_NODES * 4;
    int* gstart = (int*)w;             w += (size_t)(N_GRAPHS + 1) * 4;
    w = (char*)(((uintptr_t)w + 255) & ~(uintptr_t)255);
    int* csr_src = (int*)w;            w += (size_t)NBUCK * CAP * 4;
    w = (char*)(((uintptr_t)w + 255) & ~(uintptr_t)255);
    int* sorted = (int*)w;             w += (size_t)NBUCK * CAP * 4;
    w = (char*)(((uintptr_t)w + 255) & ~(uintptr_t)255);
    __hip_bfloat16* Wt1 = (__hip_bfloat16*)w;   w += (size_t)HDIM * HDIM * 2;
    __hip_bfloat16* Wt2 = (__hip_bfloat16*)w;   w += (size_t)HDIM * HDIM * 2;
    w = (char*)(((uintptr_t)w + 255) & ~(uintptr_t)255);
    unsigned char* hbuf = (unsigned char*)w;    w += (size_t)N_NODES * HDIM;      // fp8
    w = (char*)(((uintptr_t)w + 255) & ~(uintptr_t)255);
    __hip_bfloat16* abuf = (__hip_bfloat16*)w;  w += (size_t)N_NODES * HDIM * 2;  // bf16

    setup_kernel<<<SETUP_NBLK, 256, 0, stream>>>(batch, gstart, W1, W2, Wt1, Wt2, gcur, psum);

    scatter_kernel<<<SCAT_NBLK, 256, 0, stream>>>(srcp, dstp, gcur, sorted, N_EDGES);
    bucket_build_kernel<<<NBUCK, 256, 0, stream>>>(sorted, gcur, rs2, dis, csr_src);

    int gemm_blocks = (N_NODES + 63) / 64;
    int agg_blocks = (N_NODES + 7) / 8;

    gemm_mfma_kernel<true><<<gemm_blocks, 256, 0, stream>>>(x, Wt1, dis, hbuf, N_NODES);
    agg_kernel<false><<<agg_blocks, 256, 0, stream>>>(hbuf, dis, rs2, csr_src, b1, abuf,
                                                      batch, psum, N_NODES);
    gemm_mfma_kernel<false><<<gemm_blocks, 256, 0, stream>>>(abuf, Wt2, dis, hbuf, N_NODES);
    // layer-2 agg fuses global_mean_pool numerator: no abuf store, no pool_kernel
    agg_kernel<true><<<agg_blocks, 256, 0, stream>>>(hbuf, dis, rs2, csr_src, b2, abuf,
                                                     batch, psum, N_NODES);

    mlp_kernel<<<N_GRAPHS, 256, 0, stream>>>(psum, gstart, sv, act, Wf1, bf1, Wf2, bf2, Wo, bo, out);
}

// Round 8
// 341.328 us; speedup vs baseline: 1.0251x; 1.0251x over previous
//
#include <hip/hip_runtime.h>
#include <hip/hip_bf16.h>
#include <stdint.h>

#define N_NODES 100000
#define N_EDGES 1600000
#define N_GRAPHS 64
#define HDIM 128
#define NSLOT 64                                      // psum partial slots per graph

#define BUCKET_SHIFT 9
#define NBUCK ((N_NODES + 511) >> 9)                  // 196
#define CAP 9728                                      // real edges (mean 8192 + 11 sigma) + 512 self entries
#define SCAT_CHUNK 8192
#define SCAT_NBLK ((N_EDGES + SCAT_CHUNK - 1) / SCAT_CHUNK)  // 196
#define GB_NBLK ((N_NODES + 255) / 256)               // 391
#define PP_FLOATS (N_GRAPHS * NSLOT * HDIM)           // 524288 (2 MB)

typedef __bf16 bf16x8 __attribute__((ext_vector_type(8)));
typedef float f32x4 __attribute__((ext_vector_type(4)));
typedef float f32x2 __attribute__((ext_vector_type(2)));

// ---------------- fused setup: graph_bounds | transpose W1/W2 | init gcur/psum_part ----------------
__global__ __launch_bounds__(256) void setup_kernel(const int* __restrict__ batch,
                                                    int* __restrict__ gstart,
                                                    const float* __restrict__ W1,
                                                    const float* __restrict__ W2,
                                                    __hip_bfloat16* __restrict__ Wt1,
                                                    __hip_bfloat16* __restrict__ Wt2,
                                                    int* __restrict__ gcur,
                                                    float* __restrict__ pp) {
    int bid = blockIdx.x;
    if (bid < GB_NBLK) {
        int i = bid * 256 + threadIdx.x;
        if (i >= N_NODES) return;
        int b = batch[i];
        int prev = (i == 0) ? -1 : batch[i - 1];
        for (int g = prev + 1; g <= b; ++g) gstart[g] = i;
        if (i == N_NODES - 1) {
            for (int g = b + 1; g <= N_GRAPHS; ++g) gstart[g] = N_NODES;
        }
    } else if (bid < GB_NBLK + 128) {
        int t = bid - GB_NBLK;
        const float* W = (t < 64) ? W1 : W2;
        __hip_bfloat16* Wt = (t < 64) ? Wt1 : Wt2;
        int bb = t & 63;
        int n = bb * 2 + (threadIdx.x >> 7);
        int k = threadIdx.x & 127;
        Wt[n * 128 + k] = __float2bfloat16(W[k * 128 + n]);
    } else {
        int i = (bid - GB_NBLK - 128) * 256 + threadIdx.x;
        if (i < NBUCK) gcur[i] = i * CAP;
        int j = i - NBUCK;
        if (j >= 0 && j < PP_FLOATS) pp[j] = 0.f;
    }
}
#define SETUP_NBLK (GB_NBLK + 128 + (NBUCK + PP_FLOATS + 255) / 256)

// ---------------- scatter edges into capacity-strided buckets ----------------
// packed entry: (local_dst << 17) | src   (src < 2^17, local_dst < 512)
__global__ __launch_bounds__(256) void scatter_kernel(const int* __restrict__ src,
                                                      const int* __restrict__ dst,
                                                      int* __restrict__ gcur,
                                                      int* __restrict__ sorted, int E) {
    __shared__ int hist[NBUCK];
    __shared__ int base_s[NBUCK];
    int tid = threadIdx.x;
    int e0 = blockIdx.x * SCAT_CHUNK;
    int sv[SCAT_CHUNK / 256], dv[SCAT_CHUNK / 256];
#pragma unroll
    for (int j = 0; j < SCAT_CHUNK / 256; j++) {
        int e = e0 + (j << 8) + tid;
        if (e < E) { sv[j] = src[e]; dv[j] = dst[e]; } else { sv[j] = -1; dv[j] = -1; }
    }
    if (tid < NBUCK) hist[tid] = 0;
    __syncthreads();
#pragma unroll
    for (int j = 0; j < SCAT_CHUNK / 256; j++)
        if (dv[j] >= 0) atomicAdd(&hist[dv[j] >> BUCKET_SHIFT], 1);
    __syncthreads();
    if (tid < NBUCK) {
        int c = hist[tid];
        base_s[tid] = (c > 0) ? atomicAdd(&gcur[tid], c) : 0;
    }
    __syncthreads();
    if (tid < NBUCK) hist[tid] = 0;
    __syncthreads();
#pragma unroll
    for (int j = 0; j < SCAT_CHUNK / 256; j++) {
        if (dv[j] >= 0) {
            int b = dv[j] >> BUCKET_SHIFT;
            int idx = atomicAdd(&hist[b], 1);
            sorted[base_s[b] + idx] = ((dv[j] & 511) << 17) | sv[j];
        }
    }
}

// ---------------- per-bucket: degree, dis, row (start,end), CSR fill — LDS-staged ----------------
// Appends one self-loop entry per node at the end of its segment.
__global__ __launch_bounds__(256) void bucket_build_kernel(const int* __restrict__ sorted,
                                                           const int* __restrict__ gcur,
                                                           int2* __restrict__ rs2,
                                                           float* __restrict__ dis,
                                                           int* __restrict__ csr_src) {
    __shared__ int edges[CAP];     // 38 KB — bucket's edge list staged once
    __shared__ int cnt[512];
    __shared__ int excl[512];
    __shared__ int ps[256];
    int b = blockIdx.x, tid = threadIdx.x;
    cnt[tid] = 0; cnt[tid + 256] = 0;
    int node0 = b << BUCKET_SHIFT;
    int lo = b * CAP, hi = gcur[b];
    int ne = hi - lo;
    for (int i = tid; i < ne; i += 256) edges[i] = sorted[lo + i];
    __syncthreads();
    for (int i = tid; i < ne; i += 256)
        atomicAdd(&cnt[((unsigned)edges[i]) >> 17], 1);
    __syncthreads();
    // pair-scan of 512 counts with 256 threads
    int c0 = cnt[2 * tid], c1 = cnt[2 * tid + 1];
    ps[tid] = c0 + c1;
    __syncthreads();
#pragma unroll
    for (int off = 1; off < 256; off <<= 1) {
        int t = (tid >= off) ? ps[tid - off] : 0;
        __syncthreads();
        ps[tid] += t;
        __syncthreads();
    }
    int pex = ps[tid] - (c0 + c1);
    excl[2 * tid] = pex;
    excl[2 * tid + 1] = pex + c0;
    __syncthreads();
#pragma unroll
    for (int k = 0; k < 2; k++) {
        int li = tid + k * 256;
        int node = node0 + li;
        if (node < N_NODES) {
            // segment start shifted by li to make room for earlier nodes' self entries
            int st = lo + excl[li] + li;
            int c = cnt[li];
            rs2[node] = make_int2(st, st + c + 1);      // +1: self entry included
            dis[node] = rsqrtf((float)c + 1.0f);
            csr_src[st + c] = node;                     // self-loop entry (global id)
        }
    }
    // reuse cnt as fill cursors
    cnt[tid] = 0; cnt[tid + 256] = 0;
    __syncthreads();
    for (int i = tid; i < ne; i += 256) {
        int v = edges[i];
        int li = ((unsigned)v) >> 17;
        int idx = atomicAdd(&cnt[li], 1);
        csr_src[lo + excl[li] + li + idx] = v & 0x1FFFF;
    }
}

// ---------------- MFMA GEMM: C_fp8[r][c] = e4m3( (sum_k A[r][k] W[k][c]) * scale[r] )
template<bool A_FP32>
__global__ __launch_bounds__(256) void gemm_mfma_kernel(const void* __restrict__ Av,
                                                        const __hip_bfloat16* __restrict__ Wt,
                                                        const float* __restrict__ scale,
                                                        unsigned char* __restrict__ C, int nrows) {
    __shared__ float Cs[64 * 132];
    int tid = threadIdx.x;
    int wave = tid >> 6, lane = tid & 63;
    int quad = lane >> 4, l16 = lane & 15;
    int row0 = blockIdx.x * 64;
    int arow = row0 + wave * 16 + l16;
    int arow_c = min(arow, nrows - 1);

    const __hip_bfloat16* A16 = (const __hip_bfloat16*)Av;
    const float* A32 = (const float*)Av;

    f32x4 acc[8];
#pragma unroll
    for (int t = 0; t < 8; t++) acc[t] = (f32x4){0.f, 0.f, 0.f, 0.f};

#pragma unroll
    for (int kt = 0; kt < 4; kt++) {
        int kbase = kt * 32 + quad * 8;
        union { bf16x8 v; __hip_bfloat16 h[8]; uint4 u; } au;
        if (A_FP32) {
            const float* ap = A32 + (size_t)arow_c * 128 + kbase;
            float4 u0 = *(const float4*)ap;
            float4 u1 = *(const float4*)(ap + 4);
            au.h[0] = __float2bfloat16(u0.x); au.h[1] = __float2bfloat16(u0.y);
            au.h[2] = __float2bfloat16(u0.z); au.h[3] = __float2bfloat16(u0.w);
            au.h[4] = __float2bfloat16(u1.x); au.h[5] = __float2bfloat16(u1.y);
            au.h[6] = __float2bfloat16(u1.z); au.h[7] = __float2bfloat16(u1.w);
        } else {
            au.u = *(const uint4*)(A16 + (size_t)arow_c * 128 + kbase);
        }
#pragma unroll
        for (int t = 0; t < 8; t++) {
            bf16x8 b = *(const bf16x8*)(Wt + (size_t)(t * 16 + l16) * 128 + kbase);
            acc[t] = __builtin_amdgcn_mfma_f32_16x16x32_bf16(au.v, b, acc[t], 0, 0, 0);
        }
    }

    int rbase = wave * 16 + quad * 4;
    float s[4];
#pragma unroll
    for (int r = 0; r < 4; r++) s[r] = scale[min(row0 + rbase + r, nrows - 1)];
#pragma unroll
    for (int t = 0; t < 8; t++) {
#pragma unroll
        for (int r = 0; r < 4; r++)
            Cs[(rbase + r) * 132 + t * 16 + l16] = acc[t][r] * s[r];
    }
    __syncthreads();

#pragma unroll
    for (int p = 0; p < 4; p++) {
        int g = p * 256 + tid;
        int row = g >> 4, c8 = (g & 15) * 8;
        int grow = row0 + row;
        if (grow < nrows) {
            const float* cp = &Cs[row * 132 + c8];
            float4 v0 = *(const float4*)cp;
            float4 v1 = *(const float4*)(cp + 4);
            int w0 = __builtin_amdgcn_cvt_pk_fp8_f32(v0.x, v0.y, 0, false);
            w0 = __builtin_amdgcn_cvt_pk_fp8_f32(v0.z, v0.w, w0, true);
            int w1 = __builtin_amdgcn_cvt_pk_fp8_f32(v1.x, v1.y, 0, false);
            w1 = __builtin_amdgcn_cvt_pk_fp8_f32(v1.z, v1.w, w1, true);
            *(uint2*)(C + (size_t)grow * 128 + c8) = make_uint2((unsigned)w0, (unsigned)w1);
        }
    }
}

// ---------------- GCN aggregation: 2 nodes/wave, uint2 gathers, 8 gathers/round,
// masked single-round tail, 32-bit addressing.
// FUSE_POOL: skip abuf store; accumulate post-ReLU f32 into psum_part[graph][slot][128]
// (slot = blockIdx & 63) — spreads atomic chains 64x vs direct psum accumulation. ----------------
__device__ __forceinline__ void accum8p(f32x2* acc, uint2 u) {
    acc[0] += __builtin_amdgcn_cvt_pk_f32_fp8((int)u.x, false);
    acc[1] += __builtin_amdgcn_cvt_pk_f32_fp8((int)u.x, true);
    acc[2] += __builtin_amdgcn_cvt_pk_f32_fp8((int)u.y, false);
    acc[3] += __builtin_amdgcn_cvt_pk_f32_fp8((int)u.y, true);
}

template<bool FUSE_POOL>
__global__ __launch_bounds__(256, 8) void agg_kernel(const unsigned char* __restrict__ h8,
                                                     const float* __restrict__ dis,
                                                     const int2* __restrict__ rs2,
                                                     const int* __restrict__ csr_src,
                                                     const float* __restrict__ bias,
                                                     __hip_bfloat16* __restrict__ out,
                                                     const int* __restrict__ batch,
                                                     float* __restrict__ pp, int n) {
    __shared__ float psum_s[128];
    int tid = threadIdx.x;
    int wid = tid >> 6;
    int lane = tid & 63;
    int half = lane >> 5;          // 0: node A, 1: node B
    int q = lane >> 4;             // quarter 0..3
    int f = lane & 15;
    int l32 = lane & 31;
    int sub = q & 1;               // which of the 2 edges in this gather slot
    int hb = half << 5;            // shfl base for this half's csr chunk
    unsigned fo = (unsigned)(f * 8);
    int blk0 = (int)blockIdx.x * 8;          // first node of this block
    int slot = (int)(blockIdx.x & (NSLOT - 1));

    if (FUSE_POOL) {
        if (tid < 128) psum_s[tid] = 0.f;
        __syncthreads();
    }

    int nodeA = blk0 + wid * 2;
    bool active = nodeA < n;       // grid is exactly full at n=100000; guard kept for safety
    if (!FUSE_POOL && !active) return;
    int nodeB = nodeA + 1;
    bool hasB = nodeB < n;
    int myNode = half ? (hasB ? nodeB : nodeA) : nodeA;
    myNode = min(myNode, n - 1);

    int2 se = rs2[myNode];
    int i0 = se.x;
    int deg = se.y - se.x;         // includes self entry (>= 1)
    if ((half && !hasB) || !active) deg = 0;
    float dn = dis[myNode];

    f32x2 acc[4];
#pragma unroll
    for (int j = 0; j < 4; j++) acc[j] = (f32x2){0.f, 0.f};

    for (int base = 0; base < deg; base += 32) {
        int cnt = min(deg - base, 32);              // uniform within half
        int idx = csr_src[i0 + base + min(l32, cnt - 1)];
        int e = 0;
        // main: 16 edges per half per round, 8 independent uint2 gathers in flight
        for (; e + 16 <= cnt; e += 16) {
            int s0 = __shfl(idx, hb + e + sub, 64);
            int s1 = __shfl(idx, hb + e + 2 + sub, 64);
            int s2 = __shfl(idx, hb + e + 4 + sub, 64);
            int s3 = __shfl(idx, hb + e + 6 + sub, 64);
            int s4 = __shfl(idx, hb + e + 8 + sub, 64);
            int s5 = __shfl(idx, hb + e + 10 + sub, 64);
            int s6 = __shfl(idx, hb + e + 12 + sub, 64);
            int s7 = __shfl(idx, hb + e + 14 + sub, 64);
            uint2 u0 = *(const uint2*)(h8 + (unsigned)(s0 << 7) + fo);
            uint2 u1 = *(const uint2*)(h8 + (unsigned)(s1 << 7) + fo);
            uint2 u2 = *(const uint2*)(h8 + (unsigned)(s2 << 7) + fo);
            uint2 u3 = *(const uint2*)(h8 + (unsigned)(s3 << 7) + fo);
            uint2 u4 = *(const uint2*)(h8 + (unsigned)(s4 << 7) + fo);
            uint2 u5 = *(const uint2*)(h8 + (unsigned)(s5 << 7) + fo);
            uint2 u6 = *(const uint2*)(h8 + (unsigned)(s6 << 7) + fo);
            uint2 u7 = *(const uint2*)(h8 + (unsigned)(s7 << 7) + fo);
            accum8p(acc, u0);
            accum8p(acc, u1);
            accum8p(acc, u2);
            accum8p(acc, u3);
            accum8p(acc, u4);
            accum8p(acc, u5);
            accum8p(acc, u6);
            accum8p(acc, u7);
        }
        // tail: ONE masked round of 8 gathers covering edges e..e+15
        // (clamped index; invalid lanes zero their fp8 payload — 0x00 decodes to 0.0)
        if (e < cnt) {
            int r = cnt - 1;
#pragma unroll
            for (int k = 0; k < 8; k++) {
                int ln = e + 2 * k + sub;
                int s = __shfl(idx, hb + min(ln, r), 64);
                uint2 u = *(const uint2*)(h8 + (unsigned)(s << 7) + fo);
                if (ln > r) { u.x = 0u; u.y = 0u; }
                accum8p(acc, u);
            }
        }
    }

    // combine gather-slot pairs: Q0 += Q1 (node A), Q2 += Q3 (node B)
#pragma unroll
    for (int j = 0; j < 4; j++) {
        f32x2 v = acc[j];
        v[0] += __shfl_down(v[0], 16, 64);
        v[1] += __shfl_down(v[1], 16, 64);
        acc[j] = v;
    }

    bool res = active && (sub == 0) && (half == 0 || hasB);

    if (FUSE_POOL) {
        float rv[8];
        if (res) {
            float4 b0 = *(const float4*)(bias + f * 8);
            float4 b1 = *(const float4*)(bias + f * 8 + 4);
            float bb[8] = {b0.x, b0.y, b0.z, b0.w, b1.x, b1.y, b1.z, b1.w};
#pragma unroll
            for (int k = 0; k < 4; k++) {
                rv[2 * k]     = fmaxf(fmaf(acc[k][0], dn, bb[2 * k]), 0.f);
                rv[2 * k + 1] = fmaxf(fmaf(acc[k][1], dn, bb[2 * k + 1]), 0.f);
            }
        }
        int gA = batch[min(blk0, n - 1)];
        int gB = batch[min(blk0 + 7, n - 1)];
        if (gA == gB) {            // block-uniform branch (typical: batch sorted, 8-node blocks)
            if (res) {
#pragma unroll
                for (int k = 0; k < 8; k++) atomicAdd(&psum_s[f * 8 + k], rv[k]);
            }
            __syncthreads();
            if (tid < 128) {
                float v = psum_s[tid];
                if (v != 0.f) atomicAdd(&pp[(gA * NSLOT + slot) * 128 + tid], v);
            }
        } else {                   // graph boundary inside block (rare): per-node direct atomics
            if (res) {
                int g = batch[myNode];
#pragma unroll
                for (int k = 0; k < 8; k++)
                    atomicAdd(&pp[(g * NSLOT + slot) * 128 + f * 8 + k], rv[k]);
            }
        }
    } else {
        if (res) {
            float4 b0 = *(const float4*)(bias + f * 8);
            float4 b1 = *(const float4*)(bias + f * 8 + 4);
            float r0 = fmaxf(fmaf(acc[0][0], dn, b0.x), 0.f);
            float r1 = fmaxf(fmaf(acc[0][1], dn, b0.y), 0.f);
            float r2 = fmaxf(fmaf(acc[1][0], dn, b0.z), 0.f);
            float r3 = fmaxf(fmaf(acc[1][1], dn, b0.w), 0.f);
            float r4 = fmaxf(fmaf(acc[2][0], dn, b1.x), 0.f);
            float r5 = fmaxf(fmaf(acc[2][1], dn, b1.y), 0.f);
            float r6 = fmaxf(fmaf(acc[3][0], dn, b1.z), 0.f);
            float r7 = fmaxf(fmaf(acc[3][1], dn, b1.w), 0.f);
            __hip_bfloat162 p0 = __float22bfloat162_rn(make_float2(r0, r1));
            __hip_bfloat162 p1 = __float22bfloat162_rn(make_float2(r2, r3));
            __hip_bfloat162 p2 = __float22bfloat162_rn(make_float2(r4, r5));
            __hip_bfloat162 p3 = __float22bfloat162_rn(make_float2(r6, r7));
            uint4 pk;
            pk.x = *(unsigned int*)&p0; pk.y = *(unsigned int*)&p1;
            pk.z = *(unsigned int*)&p2; pk.w = *(unsigned int*)&p3;
            *(uint4*)(out + (size_t)myNode * 128 + f * 8) = pk;
        }
    }
}

// ---------------- fused final MLP (reduces NSLOT psum partials on load) ----------------
__global__ __launch_bounds__(256) void mlp_kernel(const float* __restrict__ pp,
                                                  const int* __restrict__ gstart,
                                                  const float* __restrict__ sv,
                                                  const float* __restrict__ act,
                                                  const float* __restrict__ Wf1,
                                                  const float* __restrict__ bf1,
                                                  const float* __restrict__ Wf2,
                                                  const float* __restrict__ bf2,
                                                  const float* __restrict__ Wo,
                                                  const float* __restrict__ bo,
                                                  float* __restrict__ out) {
    int g = blockIdx.x, tid = threadIdx.x;
    __shared__ float z[224];
    __shared__ float z1[256];
    __shared__ float red[256];
    // slot-reduction: 256 threads cover 128 feats x 2 slot-groups, then fold
    {
        int feat = tid & 127;
        int sg = tid >> 7;                 // 0 or 1: slots [0,32) or [32,64)
        float s = 0.f;
        const float* base = pp + (size_t)g * NSLOT * 128 + feat;
#pragma unroll
        for (int k = 0; k < NSLOT / 2; k++) s += base[(sg * (NSLOT / 2) + k) * 128];
        red[tid] = s;
    }
    __syncthreads();
    if (tid < 128) {
        int c = gstart[g + 1] - gstart[g];
        float cnt = fmaxf((float)c, 1.f);
        z[tid] = (red[tid] + red[tid + 128]) / cnt;
    } else if (tid < 192) {
        z[tid - 64] = 0.f;                 // placeholder; overwritten below
    }
    // fill state/action after psum part (reuse threads 128..223)
    if (tid >= 128 && tid < 192) {
        z[64 + tid] = 0.f;                 // no-op to keep structure simple
    }
    __syncthreads();
    if (tid >= 128 && tid < 192) {
        z[tid] = sv[g * 64 + (tid - 128)];
    } else if (tid >= 192 && tid < 224) {
        z[tid] = act[g * 32 + (tid - 192)];
    }
    __syncthreads();
    float a = bf1[tid];
    for (int k = 0; k < 224; k++) a = fmaf(z[k], Wf1[k * 256 + tid], a);
    z1[tid] = fmaxf(a, 0.f);
    __syncthreads();
    float b = bf2[tid];
    for (int k = 0; k < 256; k++) b = fmaf(z1[k], Wf2[k * 256 + tid], b);
    b = fmaxf(b, 0.f);
    red[tid] = b * Wo[tid];
    __syncthreads();
    for (int off = 128; off > 0; off >>= 1) {
        if (tid < off) red[tid] += red[tid + off];
        __syncthreads();
    }
    if (tid == 0) out[g] = red[0] + bo[0];
}

// ---------------- launch ----------------
extern "C" void kernel_launch(void* const* d_in, const int* in_sizes, int n_in,
                              void* d_out, int out_size, void* d_ws, size_t ws_size,
                              hipStream_t stream) {
    const float* x   = (const float*)d_in[0];
    const int*   eidx = (const int*)d_in[1];
    const int*   batch = (const int*)d_in[2];
    const float* sv  = (const float*)d_in[3];
    const float* act = (const float*)d_in[4];
    const float* W1  = (const float*)d_in[5];
    const float* b1  = (const float*)d_in[6];
    const float* W2  = (const float*)d_in[7];
    const float* b2  = (const float*)d_in[8];
    const float* Wf1 = (const float*)d_in[9];
    const float* bf1 = (const float*)d_in[10];
    const float* Wf2 = (const float*)d_in[11];
    const float* bf2 = (const float*)d_in[12];
    const float* Wo  = (const float*)d_in[13];
    const float* bo  = (const float*)d_in[14];
    float* out = (float*)d_out;

    const int* srcp = eidx;             // edge_index[0]
    const int* dstp = eidx + N_EDGES;   // edge_index[1]

    char* w = (char*)d_ws;
    int* gcur = (int*)w;               w += (size_t)NBUCK * 4;
    int2* rs2 = (int2*)w;              w += (size_t)N_NODES * 8;
    float* dis = (float*)w;            w += (size_t)N_NODES * 4;
    int* gstart = (int*)w;             w += (size_t)(N_GRAPHS + 1) * 4;
    w = (char*)(((uintptr_t)w + 255) & ~(uintptr_t)255);
    float* pp = (float*)w;             w += (size_t)PP_FLOATS * 4;              // 2 MB partials
    w = (char*)(((uintptr_t)w + 255) & ~(uintptr_t)255);
    int* csr_src = (int*)w;            w += (size_t)NBUCK * CAP * 4;
    w = (char*)(((uintptr_t)w + 255) & ~(uintptr_t)255);
    int* sorted = (int*)w;             w += (size_t)NBUCK * CAP * 4;
    w = (char*)(((uintptr_t)w + 255) & ~(uintptr_t)255);
    __hip_bfloat16* Wt1 = (__hip_bfloat16*)w;   w += (size_t)HDIM * HDIM * 2;
    __hip_bfloat16* Wt2 = (__hip_bfloat16*)w;   w += (size_t)HDIM * HDIM * 2;
    w = (char*)(((uintptr_t)w + 255) & ~(uintptr_t)255);
    unsigned char* hbuf = (unsigned char*)w;    w += (size_t)N_NODES * HDIM;      // fp8
    w = (char*)(((uintptr_t)w + 255) & ~(uintptr_t)255);
    __hip_bfloat16* abuf = (__hip_bfloat16*)w;  w += (size_t)N_NODES * HDIM * 2;  // bf16

    setup_kernel<<<SETUP_NBLK, 256, 0, stream>>>(batch, gstart, W1, W2, Wt1, Wt2, gcur, pp);

    scatter_kernel<<<SCAT_NBLK, 256, 0, stream>>>(srcp, dstp, gcur, sorted, N_EDGES);
    bucket_build_kernel<<<NBUCK, 256, 0, stream>>>(sorted, gcur, rs2, dis, csr_src);

    int gemm_blocks = (N_NODES + 63) / 64;
    int agg_blocks = (N_NODES + 7) / 8;

    gemm_mfma_kernel<true><<<gemm_blocks, 256, 0, stream>>>(x, Wt1, dis, hbuf, N_NODES);
    agg_kernel<false><<<agg_blocks, 256, 0, stream>>>(hbuf, dis, rs2, csr_src, b1, abuf,
                                                      batch, pp, N_NODES);
    gemm_mfma_kernel<false><<<gemm_blocks, 256, 0, stream>>>(abuf, Wt2, dis, hbuf, N_NODES);
    // layer-2 agg fuses global_mean_pool numerator into slot-spread partials
    agg_kernel<true><<<agg_blocks, 256, 0, stream>>>(hbuf, dis, rs2, csr_src, b2, abuf,
                                                     batch, pp, N_NODES);

    mlp_kernel<<<N_GRAPHS, 256, 0, stream>>>(pp, gstart, sv, act, Wf1, bf1, Wf2, bf2, Wo, bo, out);
}

// Round 9
// 309.923 us; speedup vs baseline: 1.1290x; 1.1013x over previous
//
#include <hip/hip_runtime.h>
#include <hip/hip_bf16.h>
#include <stdint.h>

#define N_NODES 100000
#define N_EDGES 1600000
#define N_GRAPHS 64
#define HDIM 128

#define BUCKET_SHIFT 9
#define NBUCK ((N_NODES + 511) >> 9)                  // 196
#define CAP 9728                                      // real edges (mean 8192 + 11 sigma) + 512 self entries
#define SCAT_CHUNK 8192
#define SCAT_NBLK ((N_EDGES + SCAT_CHUNK - 1) / SCAT_CHUNK)  // 196
#define GB_NBLK ((N_NODES + 255) / 256)               // 391
#define NPB ((N_NODES + 7) / 8)                       // 12500 agg blocks (exact: 100000/8)

typedef __bf16 bf16x8 __attribute__((ext_vector_type(8)));
typedef float f32x4 __attribute__((ext_vector_type(4)));
typedef float f32x2 __attribute__((ext_vector_type(2)));

// ---------------- fused setup: graph_bounds | transpose W1/W2 | init gcur/psum0 ----------------
__global__ __launch_bounds__(256) void setup_kernel(const int* __restrict__ batch,
                                                    int* __restrict__ gstart,
                                                    const float* __restrict__ W1,
                                                    const float* __restrict__ W2,
                                                    __hip_bfloat16* __restrict__ Wt1,
                                                    __hip_bfloat16* __restrict__ Wt2,
                                                    int* __restrict__ gcur,
                                                    float* __restrict__ psum0) {
    int bid = blockIdx.x;
    if (bid < GB_NBLK) {
        int i = bid * 256 + threadIdx.x;
        if (i >= N_NODES) return;
        int b = batch[i];
        int prev = (i == 0) ? -1 : batch[i - 1];
        for (int g = prev + 1; g <= b; ++g) gstart[g] = i;
        if (i == N_NODES - 1) {
            for (int g = b + 1; g <= N_GRAPHS; ++g) gstart[g] = N_NODES;
        }
    } else if (bid < GB_NBLK + 128) {
        int t = bid - GB_NBLK;
        const float* W = (t < 64) ? W1 : W2;
        __hip_bfloat16* Wt = (t < 64) ? Wt1 : Wt2;
        int bb = t & 63;
        int n = bb * 2 + (threadIdx.x >> 7);
        int k = threadIdx.x & 127;
        Wt[n * 128 + k] = __float2bfloat16(W[k * 128 + n]);
    } else {
        int i = (bid - GB_NBLK - 128) * 256 + threadIdx.x;
        if (i < NBUCK) gcur[i] = i * CAP;
        int j = i - NBUCK;
        if (j >= 0 && j < N_GRAPHS * HDIM) psum0[j] = 0.f;
    }
}
#define SETUP_NBLK (GB_NBLK + 128 + (NBUCK + N_GRAPHS * HDIM + 255) / 256)

// ---------------- scatter edges into capacity-strided buckets ----------------
// packed entry: (local_dst << 17) | src   (src < 2^17, local_dst < 512)
__global__ __launch_bounds__(256) void scatter_kernel(const int* __restrict__ src,
                                                      const int* __restrict__ dst,
                                                      int* __restrict__ gcur,
                                                      int* __restrict__ sorted, int E) {
    __shared__ int hist[NBUCK];
    __shared__ int base_s[NBUCK];
    int tid = threadIdx.x;
    int e0 = blockIdx.x * SCAT_CHUNK;
    int sv[SCAT_CHUNK / 256], dv[SCAT_CHUNK / 256];
#pragma unroll
    for (int j = 0; j < SCAT_CHUNK / 256; j++) {
        int e = e0 + (j << 8) + tid;
        if (e < E) { sv[j] = src[e]; dv[j] = dst[e]; } else { sv[j] = -1; dv[j] = -1; }
    }
    if (tid < NBUCK) hist[tid] = 0;
    __syncthreads();
#pragma unroll
    for (int j = 0; j < SCAT_CHUNK / 256; j++)
        if (dv[j] >= 0) atomicAdd(&hist[dv[j] >> BUCKET_SHIFT], 1);
    __syncthreads();
    if (tid < NBUCK) {
        int c = hist[tid];
        base_s[tid] = (c > 0) ? atomicAdd(&gcur[tid], c) : 0;
    }
    __syncthreads();
    if (tid < NBUCK) hist[tid] = 0;
    __syncthreads();
#pragma unroll
    for (int j = 0; j < SCAT_CHUNK / 256; j++) {
        if (dv[j] >= 0) {
            int b = dv[j] >> BUCKET_SHIFT;
            int idx = atomicAdd(&hist[b], 1);
            sorted[base_s[b] + idx] = ((dv[j] & 511) << 17) | sv[j];
        }
    }
}

// ---------------- per-bucket: degree, dis, row (start,end), CSR fill — LDS-staged ----------------
// Appends one self-loop entry per node at the end of its segment.
__global__ __launch_bounds__(256) void bucket_build_kernel(const int* __restrict__ sorted,
                                                           const int* __restrict__ gcur,
                                                           int2* __restrict__ rs2,
                                                           float* __restrict__ dis,
                                                           int* __restrict__ csr_src) {
    __shared__ int edges[CAP];     // 38 KB — bucket's edge list staged once
    __shared__ int cnt[512];
    __shared__ int excl[512];
    __shared__ int ps[256];
    int b = blockIdx.x, tid = threadIdx.x;
    cnt[tid] = 0; cnt[tid + 256] = 0;
    int node0 = b << BUCKET_SHIFT;
    int lo = b * CAP, hi = gcur[b];
    int ne = hi - lo;
    for (int i = tid; i < ne; i += 256) edges[i] = sorted[lo + i];
    __syncthreads();
    for (int i = tid; i < ne; i += 256)
        atomicAdd(&cnt[((unsigned)edges[i]) >> 17], 1);
    __syncthreads();
    // pair-scan of 512 counts with 256 threads
    int c0 = cnt[2 * tid], c1 = cnt[2 * tid + 1];
    ps[tid] = c0 + c1;
    __syncthreads();
#pragma unroll
    for (int off = 1; off < 256; off <<= 1) {
        int t = (tid >= off) ? ps[tid - off] : 0;
        __syncthreads();
        ps[tid] += t;
        __syncthreads();
    }
    int pex = ps[tid] - (c0 + c1);
    excl[2 * tid] = pex;
    excl[2 * tid + 1] = pex + c0;
    __syncthreads();
#pragma unroll
    for (int k = 0; k < 2; k++) {
        int li = tid + k * 256;
        int node = node0 + li;
        if (node < N_NODES) {
            // segment start shifted by li to make room for earlier nodes' self entries
            int st = lo + excl[li] + li;
            int c = cnt[li];
            rs2[node] = make_int2(st, st + c + 1);      // +1: self entry included
            dis[node] = rsqrtf((float)c + 1.0f);
            csr_src[st + c] = node;                     // self-loop entry (global id)
        }
    }
    // reuse cnt as fill cursors
    cnt[tid] = 0; cnt[tid + 256] = 0;
    __syncthreads();
    for (int i = tid; i < ne; i += 256) {
        int v = edges[i];
        int li = ((unsigned)v) >> 17;
        int idx = atomicAdd(&cnt[li], 1);
        csr_src[lo + excl[li] + li + idx] = v & 0x1FFFF;
    }
}

// ---------------- MFMA GEMM: C_fp8[r][c] = e4m3( (sum_k A[r][k] W[k][c]) * scale[r] )
template<bool A_FP32>
__global__ __launch_bounds__(256) void gemm_mfma_kernel(const void* __restrict__ Av,
                                                        const __hip_bfloat16* __restrict__ Wt,
                                                        const float* __restrict__ scale,
                                                        unsigned char* __restrict__ C, int nrows) {
    __shared__ float Cs[64 * 132];
    int tid = threadIdx.x;
    int wave = tid >> 6, lane = tid & 63;
    int quad = lane >> 4, l16 = lane & 15;
    int row0 = blockIdx.x * 64;
    int arow = row0 + wave * 16 + l16;
    int arow_c = min(arow, nrows - 1);

    const __hip_bfloat16* A16 = (const __hip_bfloat16*)Av;
    const float* A32 = (const float*)Av;

    f32x4 acc[8];
#pragma unroll
    for (int t = 0; t < 8; t++) acc[t] = (f32x4){0.f, 0.f, 0.f, 0.f};

#pragma unroll
    for (int kt = 0; kt < 4; kt++) {
        int kbase = kt * 32 + quad * 8;
        union { bf16x8 v; __hip_bfloat16 h[8]; uint4 u; } au;
        if (A_FP32) {
            const float* ap = A32 + (size_t)arow_c * 128 + kbase;
            float4 u0 = *(const float4*)ap;
            float4 u1 = *(const float4*)(ap + 4);
            au.h[0] = __float2bfloat16(u0.x); au.h[1] = __float2bfloat16(u0.y);
            au.h[2] = __float2bfloat16(u0.z); au.h[3] = __float2bfloat16(u0.w);
            au.h[4] = __float2bfloat16(u1.x); au.h[5] = __float2bfloat16(u1.y);
            au.h[6] = __float2bfloat16(u1.z); au.h[7] = __float2bfloat16(u1.w);
        } else {
            au.u = *(const uint4*)(A16 + (size_t)arow_c * 128 + kbase);
        }
#pragma unroll
        for (int t = 0; t < 8; t++) {
            bf16x8 b = *(const bf16x8*)(Wt + (size_t)(t * 16 + l16) * 128 + kbase);
            acc[t] = __builtin_amdgcn_mfma_f32_16x16x32_bf16(au.v, b, acc[t], 0, 0, 0);
        }
    }

    int rbase = wave * 16 + quad * 4;
    float s[4];
#pragma unroll
    for (int r = 0; r < 4; r++) s[r] = scale[min(row0 + rbase + r, nrows - 1)];
#pragma unroll
    for (int t = 0; t < 8; t++) {
#pragma unroll
        for (int r = 0; r < 4; r++)
            Cs[(rbase + r) * 132 + t * 16 + l16] = acc[t][r] * s[r];
    }
    __syncthreads();

#pragma unroll
    for (int p = 0; p < 4; p++) {
        int g = p * 256 + tid;
        int row = g >> 4, c8 = (g & 15) * 8;
        int grow = row0 + row;
        if (grow < nrows) {
            const float* cp = &Cs[row * 132 + c8];
            float4 v0 = *(const float4*)cp;
            float4 v1 = *(const float4*)(cp + 4);
            int w0 = __builtin_amdgcn_cvt_pk_fp8_f32(v0.x, v0.y, 0, false);
            w0 = __builtin_amdgcn_cvt_pk_fp8_f32(v0.z, v0.w, w0, true);
            int w1 = __builtin_amdgcn_cvt_pk_fp8_f32(v1.x, v1.y, 0, false);
            w1 = __builtin_amdgcn_cvt_pk_fp8_f32(v1.z, v1.w, w1, true);
            *(uint2*)(C + (size_t)grow * 128 + c8) = make_uint2((unsigned)w0, (unsigned)w1);
        }
    }
}

// ---------------- GCN aggregation: 2 nodes/wave, uint2 gathers, 8 gathers/round,
// masked single-round tail, 32-bit addressing.
// FUSE_POOL: NO ATOMICS in common path — per-wave shfl combine -> plain LDS writes ->
// one non-atomic 512B block-partial store to pp[blockIdx]. Boundary blocks (rare) use
// per-node atomics into tiny psum0[64][128]. mlp reduces pp + psum0. ----------------
__device__ __forceinline__ void accum8p(f32x2* acc, uint2 u) {
    acc[0] += __builtin_amdgcn_cvt_pk_f32_fp8((int)u.x, false);
    acc[1] += __builtin_amdgcn_cvt_pk_f32_fp8((int)u.x, true);
    acc[2] += __builtin_amdgcn_cvt_pk_f32_fp8((int)u.y, false);
    acc[3] += __builtin_amdgcn_cvt_pk_f32_fp8((int)u.y, true);
}

template<bool FUSE_POOL>
__global__ __launch_bounds__(256, 8) void agg_kernel(const unsigned char* __restrict__ h8,
                                                     const float* __restrict__ dis,
                                                     const int2* __restrict__ rs2,
                                                     const int* __restrict__ csr_src,
                                                     const float* __restrict__ bias,
                                                     __hip_bfloat16* __restrict__ out,
                                                     const int* __restrict__ batch,
                                                     float* __restrict__ pp,
                                                     float* __restrict__ psum0, int n) {
    __shared__ float psum_s[512];          // 4 waves x 128 feats (FUSE_POOL only)
    int tid = threadIdx.x;
    int wid = tid >> 6;
    int lane = tid & 63;
    int half = lane >> 5;          // 0: node A, 1: node B
    int q = lane >> 4;             // quarter 0..3
    int f = lane & 15;
    int l32 = lane & 31;
    int sub = q & 1;               // which of the 2 edges in this gather slot
    int hb = half << 5;            // shfl base for this half's csr chunk
    unsigned fo = (unsigned)(f * 8);
    int blk0 = (int)blockIdx.x * 8;          // first node of this block

    if (FUSE_POOL) {
        psum_s[tid] = 0.f; psum_s[tid + 256] = 0.f;
        __syncthreads();
    }

    int nodeA = blk0 + wid * 2;
    bool active = nodeA < n;       // grid is exactly full at n=100000; guard kept for safety
    if (!FUSE_POOL && !active) return;
    int nodeB = nodeA + 1;
    bool hasB = nodeB < n;
    int myNode = half ? (hasB ? nodeB : nodeA) : nodeA;
    myNode = min(myNode, n - 1);

    int2 se = rs2[myNode];
    int i0 = se.x;
    int deg = se.y - se.x;         // includes self entry (>= 1)
    if ((half && !hasB) || !active) deg = 0;
    float dn = dis[myNode];

    f32x2 acc[4];
#pragma unroll
    for (int j = 0; j < 4; j++) acc[j] = (f32x2){0.f, 0.f};

    for (int base = 0; base < deg; base += 32) {
        int cnt = min(deg - base, 32);              // uniform within half
        int idx = csr_src[i0 + base + min(l32, cnt - 1)];
        int e = 0;
        // main: 16 edges per half per round, 8 independent uint2 gathers in flight
        for (; e + 16 <= cnt; e += 16) {
            int s0 = __shfl(idx, hb + e + sub, 64);
            int s1 = __shfl(idx, hb + e + 2 + sub, 64);
            int s2 = __shfl(idx, hb + e + 4 + sub, 64);
            int s3 = __shfl(idx, hb + e + 6 + sub, 64);
            int s4 = __shfl(idx, hb + e + 8 + sub, 64);
            int s5 = __shfl(idx, hb + e + 10 + sub, 64);
            int s6 = __shfl(idx, hb + e + 12 + sub, 64);
            int s7 = __shfl(idx, hb + e + 14 + sub, 64);
            uint2 u0 = *(const uint2*)(h8 + (unsigned)(s0 << 7) + fo);
            uint2 u1 = *(const uint2*)(h8 + (unsigned)(s1 << 7) + fo);
            uint2 u2 = *(const uint2*)(h8 + (unsigned)(s2 << 7) + fo);
            uint2 u3 = *(const uint2*)(h8 + (unsigned)(s3 << 7) + fo);
            uint2 u4 = *(const uint2*)(h8 + (unsigned)(s4 << 7) + fo);
            uint2 u5 = *(const uint2*)(h8 + (unsigned)(s5 << 7) + fo);
            uint2 u6 = *(const uint2*)(h8 + (unsigned)(s6 << 7) + fo);
            uint2 u7 = *(const uint2*)(h8 + (unsigned)(s7 << 7) + fo);
            accum8p(acc, u0);
            accum8p(acc, u1);
            accum8p(acc, u2);
            accum8p(acc, u3);
            accum8p(acc, u4);
            accum8p(acc, u5);
            accum8p(acc, u6);
            accum8p(acc, u7);
        }
        // tail: ONE masked round of 8 gathers covering edges e..e+15
        // (clamped index; invalid lanes zero their fp8 payload — 0x00 decodes to 0.0)
        if (e < cnt) {
            int r = cnt - 1;
#pragma unroll
            for (int k = 0; k < 8; k++) {
                int ln = e + 2 * k + sub;
                int s = __shfl(idx, hb + min(ln, r), 64);
                uint2 u = *(const uint2*)(h8 + (unsigned)(s << 7) + fo);
                if (ln > r) { u.x = 0u; u.y = 0u; }
                accum8p(acc, u);
            }
        }
    }

    // combine gather-slot pairs: Q0 += Q1 (node A), Q2 += Q3 (node B)
#pragma unroll
    for (int j = 0; j < 4; j++) {
        f32x2 v = acc[j];
        v[0] += __shfl_down(v[0], 16, 64);
        v[1] += __shfl_down(v[1], 16, 64);
        acc[j] = v;
    }

    bool res = active && (sub == 0) && (half == 0 || hasB);

    if (FUSE_POOL) {
        // per-node ReLU(bias + dn*acc) on q0 (node A) and q2 (node B) lanes
        float rv[8];
        {
            float4 b0 = *(const float4*)(bias + f * 8);
            float4 b1 = *(const float4*)(bias + f * 8 + 4);
            float bb[8] = {b0.x, b0.y, b0.z, b0.w, b1.x, b1.y, b1.z, b1.w};
#pragma unroll
            for (int k = 0; k < 4; k++) {
                rv[2 * k]     = fmaxf(fmaf(acc[k][0], dn, bb[2 * k]), 0.f);
                rv[2 * k + 1] = fmaxf(fmaf(acc[k][1], dn, bb[2 * k + 1]), 0.f);
            }
        }
        int gA = batch[blk0];
        int gB = batch[min(blk0 + 7, n - 1)];
        if (gA == gB) {
            // fold node B (q2 lanes) into node A lanes (q0): graph-sum only needs totals
#pragma unroll
            for (int k = 0; k < 8; k++) rv[k] += __shfl_down(rv[k], 32, 64);
            if (lane < 16 && active) {
#pragma unroll
                for (int k = 0; k < 8; k++) psum_s[wid * 128 + f * 8 + k] = rv[k];
            }
            __syncthreads();
            if (tid < 128) {
                float v = psum_s[tid] + psum_s[128 + tid] + psum_s[256 + tid] + psum_s[384 + tid];
                pp[(size_t)blockIdx.x * 128 + tid] = v;   // non-atomic block partial
            }
        } else {
            // graph boundary inside block (rare): per-node atomics into psum0
            if (res) {
                int g = batch[myNode];
#pragma unroll
                for (int k = 0; k < 8; k++)
                    atomicAdd(&psum0[g * 128 + f * 8 + k], rv[k]);
            }
        }
    } else {
        if (res) {
            float4 b0 = *(const float4*)(bias + f * 8);
            float4 b1 = *(const float4*)(bias + f * 8 + 4);
            float r0 = fmaxf(fmaf(acc[0][0], dn, b0.x), 0.f);
            float r1 = fmaxf(fmaf(acc[0][1], dn, b0.y), 0.f);
            float r2 = fmaxf(fmaf(acc[1][0], dn, b0.z), 0.f);
            float r3 = fmaxf(fmaf(acc[1][1], dn, b0.w), 0.f);
            float r4 = fmaxf(fmaf(acc[2][0], dn, b1.x), 0.f);
            float r5 = fmaxf(fmaf(acc[2][1], dn, b1.y), 0.f);
            float r6 = fmaxf(fmaf(acc[3][0], dn, b1.z), 0.f);
            float r7 = fmaxf(fmaf(acc[3][1], dn, b1.w), 0.f);
            __hip_bfloat162 p0 = __float22bfloat162_rn(make_float2(r0, r1));
            __hip_bfloat162 p1 = __float22bfloat162_rn(make_float2(r2, r3));
            __hip_bfloat162 p2 = __float22bfloat162_rn(make_float2(r4, r5));
            __hip_bfloat162 p3 = __float22bfloat162_rn(make_float2(r6, r7));
            uint4 pk;
            pk.x = *(unsigned int*)&p0; pk.y = *(unsigned int*)&p1;
            pk.z = *(unsigned int*)&p2; pk.w = *(unsigned int*)&p3;
            *(uint4*)(out + (size_t)myNode * 128 + f * 8) = pk;
        }
    }
}

// ---------------- fused final MLP (reduces per-block pool partials + boundary psum0) ----------------
__global__ __launch_bounds__(256) void mlp_kernel(const float* __restrict__ pp,
                                                  const float* __restrict__ psum0,
                                                  const int* __restrict__ gstart,
                                                  const float* __restrict__ sv,
                                                  const float* __restrict__ act,
                                                  const float* __restrict__ Wf1,
                                                  const float* __restrict__ bf1,
                                                  const float* __restrict__ Wf2,
                                                  const float* __restrict__ bf2,
                                                  const float* __restrict__ Wo,
                                                  const float* __restrict__ bo,
                                                  float* __restrict__ out) {
    int g = blockIdx.x, tid = threadIdx.x;
    __shared__ float z[224];
    __shared__ float z1[256];
    __shared__ float red[256];
    // reduce block partials for graph g: blocks fully inside [gstart[g], gstart[g+1])
    int lo = gstart[g], hi = gstart[g + 1];
    int b_lo = (lo + 7) >> 3;
    int b_hi = hi >> 3;                    // exclusive
    {
        int feat = tid & 127;
        int sg = tid >> 7;                 // 2-way split over blocks for ILP
        float s = 0.f;
        for (int b = b_lo + sg; b < b_hi; b += 2)
            s += pp[(size_t)b * 128 + feat];
        red[tid] = s;
    }
    __syncthreads();
    if (tid < 128) {
        float cnt = fmaxf((float)(hi - lo), 1.f);
        z[tid] = (red[tid] + red[tid + 128] + psum0[g * 128 + tid]) / cnt;
    } else if (tid < 192) {
        z[tid] = sv[g * 64 + (tid - 128)];
    } else if (tid < 224) {
        z[tid] = act[g * 32 + (tid - 192)];
    }
    __syncthreads();
    float a = bf1[tid];
    for (int k = 0; k < 224; k++) a = fmaf(z[k], Wf1[k * 256 + tid], a);
    z1[tid] = fmaxf(a, 0.f);
    __syncthreads();
    float b = bf2[tid];
    for (int k = 0; k < 256; k++) b = fmaf(z1[k], Wf2[k * 256 + tid], b);
    b = fmaxf(b, 0.f);
    red[tid] = b * Wo[tid];
    __syncthreads();
    for (int off = 128; off > 0; off >>= 1) {
        if (tid < off) red[tid] += red[tid + off];
        __syncthreads();
    }
    if (tid == 0) out[g] = red[0] + bo[0];
}

// ---------------- launch ----------------
extern "C" void kernel_launch(void* const* d_in, const int* in_sizes, int n_in,
                              void* d_out, int out_size, void* d_ws, size_t ws_size,
                              hipStream_t stream) {
    const float* x   = (const float*)d_in[0];
    const int*   eidx = (const int*)d_in[1];
    const int*   batch = (const int*)d_in[2];
    const float* sv  = (const float*)d_in[3];
    const float* act = (const float*)d_in[4];
    const float* W1  = (const float*)d_in[5];
    const float* b1  = (const float*)d_in[6];
    const float* W2  = (const float*)d_in[7];
    const float* b2  = (const float*)d_in[8];
    const float* Wf1 = (const float*)d_in[9];
    const float* bf1 = (const float*)d_in[10];
    const float* Wf2 = (const float*)d_in[11];
    const float* bf2 = (const float*)d_in[12];
    const float* Wo  = (const float*)d_in[13];
    const float* bo  = (const float*)d_in[14];
    float* out = (float*)d_out;

    const int* srcp = eidx;             // edge_index[0]
    const int* dstp = eidx + N_EDGES;   // edge_index[1]

    char* w = (char*)d_ws;
    int* gcur = (int*)w;               w += (size_t)NBUCK * 4;
    int2* rs2 = (int2*)w;              w += (size_t)N_NODES * 8;
    float* dis = (float*)w;            w += (size_t)N_NODES * 4;
    int* gstart = (int*)w;             w += (size_t)(N_GRAPHS + 1) * 4;
    w = (char*)(((uintptr_t)w + 255) & ~(uintptr_t)255);
    float* pp = (float*)w;             w += (size_t)NPB * HDIM * 4;              // 6.4 MB block partials
    float* psum0 = (float*)w;          w += (size_t)N_GRAPHS * HDIM * 4;         // boundary partials
    w = (char*)(((uintptr_t)w + 255) & ~(uintptr_t)255);
    int* csr_src = (int*)w;            w += (size_t)NBUCK * CAP * 4;
    w = (char*)(((uintptr_t)w + 255) & ~(uintptr_t)255);
    int* sorted = (int*)w;             w += (size_t)NBUCK * CAP * 4;
    w = (char*)(((uintptr_t)w + 255) & ~(uintptr_t)255);
    __hip_bfloat16* Wt1 = (__hip_bfloat16*)w;   w += (size_t)HDIM * HDIM * 2;
    __hip_bfloat16* Wt2 = (__hip_bfloat16*)w;   w += (size_t)HDIM * HDIM * 2;
    w = (char*)(((uintptr_t)w + 255) & ~(uintptr_t)255);
    unsigned char* hbuf = (unsigned char*)w;    w += (size_t)N_NODES * HDIM;      // fp8
    w = (char*)(((uintptr_t)w + 255) & ~(uintptr_t)255);
    __hip_bfloat16* abuf = (__hip_bfloat16*)w;  w += (size_t)N_NODES * HDIM * 2;  // bf16

    setup_kernel<<<SETUP_NBLK, 256, 0, stream>>>(batch, gstart, W1, W2, Wt1, Wt2, gcur, psum0);

    scatter_kernel<<<SCAT_NBLK, 256, 0, stream>>>(srcp, dstp, gcur, sorted, N_EDGES);
    bucket_build_kernel<<<NBUCK, 256, 0, stream>>>(sorted, gcur, rs2, dis, csr_src);

    int gemm_blocks = (N_NODES + 63) / 64;

    gemm_mfma_kernel<true><<<gemm_blocks, 256, 0, stream>>>(x, Wt1, dis, hbuf, N_NODES);
    agg_kernel<false><<<NPB, 256, 0, stream>>>(hbuf, dis, rs2, csr_src, b1, abuf,
                                               batch, pp, psum0, N_NODES);
    gemm_mfma_kernel<false><<<gemm_blocks, 256, 0, stream>>>(abuf, Wt2, dis, hbuf, N_NODES);
    // layer-2 agg fuses global_mean_pool numerator: atomic-free block partials
    agg_kernel<true><<<NPB, 256, 0, stream>>>(hbuf, dis, rs2, csr_src, b2, abuf,
                                              batch, pp, psum0, N_NODES);

    mlp_kernel<<<N_GRAPHS, 256, 0, stream>>>(pp, psum0, gstart, sv, act,
                                             Wf1, bf1, Wf2, bf2, Wo, bo, out);
}

// Round 10
// 296.320 us; speedup vs baseline: 1.1808x; 1.0459x over previous
//
#include <hip/hip_runtime.h>
#include <hip/hip_bf16.h>
#include <stdint.h>

#define N_NODES 100000
#define N_EDGES 1600000
#define N_GRAPHS 64
#define HDIM 128

#define BUCKET_SHIFT 9
#define NBUCK ((N_NODES + 511) >> 9)                  // 196
#define CAP 9728                                      // real edges (mean 8192 + 11 sigma) + 512 self entries
#define SCAT_CHUNK 8192
#define SCAT_NBLK ((N_EDGES + SCAT_CHUNK - 1) / SCAT_CHUNK)  // 196
#define GB_NBLK ((N_NODES + 255) / 256)               // 391
#define NPB ((N_NODES + 7) / 8)                       // 12500 agg blocks (exact: 100000/8)
#define RED_CHUNKS 8                                  // pool-reduce chunks per graph

typedef __bf16 bf16x8 __attribute__((ext_vector_type(8)));
typedef float f32x4 __attribute__((ext_vector_type(4)));
typedef float f32x2 __attribute__((ext_vector_type(2)));

// ---------------- fused setup: graph_bounds | transpose W1/W2 | init gcur/psum0 ----------------
__global__ __launch_bounds__(256) void setup_kernel(const int* __restrict__ batch,
                                                    int* __restrict__ gstart,
                                                    const float* __restrict__ W1,
                                                    const float* __restrict__ W2,
                                                    __hip_bfloat16* __restrict__ Wt1,
                                                    __hip_bfloat16* __restrict__ Wt2,
                                                    int* __restrict__ gcur,
                                                    float* __restrict__ psum0) {
    int bid = blockIdx.x;
    if (bid < GB_NBLK) {
        int i = bid * 256 + threadIdx.x;
        if (i >= N_NODES) return;
        int b = batch[i];
        int prev = (i == 0) ? -1 : batch[i - 1];
        for (int g = prev + 1; g <= b; ++g) gstart[g] = i;
        if (i == N_NODES - 1) {
            for (int g = b + 1; g <= N_GRAPHS; ++g) gstart[g] = N_NODES;
        }
    } else if (bid < GB_NBLK + 128) {
        int t = bid - GB_NBLK;
        const float* W = (t < 64) ? W1 : W2;
        __hip_bfloat16* Wt = (t < 64) ? Wt1 : Wt2;
        int bb = t & 63;
        int n = bb * 2 + (threadIdx.x >> 7);
        int k = threadIdx.x & 127;
        Wt[n * 128 + k] = __float2bfloat16(W[k * 128 + n]);
    } else {
        int i = (bid - GB_NBLK - 128) * 256 + threadIdx.x;
        if (i < NBUCK) gcur[i] = i * CAP;
        int j = i - NBUCK;
        if (j >= 0 && j < N_GRAPHS * HDIM) psum0[j] = 0.f;
    }
}
#define SETUP_NBLK (GB_NBLK + 128 + (NBUCK + N_GRAPHS * HDIM + 255) / 256)

// ---------------- scatter edges into capacity-strided buckets ----------------
// packed entry: (local_dst << 17) | src   (src < 2^17, local_dst < 512)
__global__ __launch_bounds__(256) void scatter_kernel(const int* __restrict__ src,
                                                      const int* __restrict__ dst,
                                                      int* __restrict__ gcur,
                                                      int* __restrict__ sorted, int E) {
    __shared__ int hist[NBUCK];
    __shared__ int base_s[NBUCK];
    int tid = threadIdx.x;
    int e0 = blockIdx.x * SCAT_CHUNK;
    int sv[SCAT_CHUNK / 256], dv[SCAT_CHUNK / 256];
#pragma unroll
    for (int j = 0; j < SCAT_CHUNK / 256; j++) {
        int e = e0 + (j << 8) + tid;
        if (e < E) { sv[j] = src[e]; dv[j] = dst[e]; } else { sv[j] = -1; dv[j] = -1; }
    }
    if (tid < NBUCK) hist[tid] = 0;
    __syncthreads();
#pragma unroll
    for (int j = 0; j < SCAT_CHUNK / 256; j++)
        if (dv[j] >= 0) atomicAdd(&hist[dv[j] >> BUCKET_SHIFT], 1);
    __syncthreads();
    if (tid < NBUCK) {
        int c = hist[tid];
        base_s[tid] = (c > 0) ? atomicAdd(&gcur[tid], c) : 0;
    }
    __syncthreads();
    if (tid < NBUCK) hist[tid] = 0;
    __syncthreads();
#pragma unroll
    for (int j = 0; j < SCAT_CHUNK / 256; j++) {
        if (dv[j] >= 0) {
            int b = dv[j] >> BUCKET_SHIFT;
            int idx = atomicAdd(&hist[b], 1);
            sorted[base_s[b] + idx] = ((dv[j] & 511) << 17) | sv[j];
        }
    }
}

// ---------------- per-bucket: degree, dis, row (start,end), CSR fill — LDS-staged ----------------
// Appends one self-loop entry per node at the end of its segment.
__global__ __launch_bounds__(256) void bucket_build_kernel(const int* __restrict__ sorted,
                                                           const int* __restrict__ gcur,
                                                           int2* __restrict__ rs2,
                                                           float* __restrict__ dis,
                                                           int* __restrict__ csr_src) {
    __shared__ int edges[CAP];     // 38 KB — bucket's edge list staged once
    __shared__ int cnt[512];
    __shared__ int excl[512];
    __shared__ int ps[256];
    int b = blockIdx.x, tid = threadIdx.x;
    cnt[tid] = 0; cnt[tid + 256] = 0;
    int node0 = b << BUCKET_SHIFT;
    int lo = b * CAP, hi = gcur[b];
    int ne = hi - lo;
    for (int i = tid; i < ne; i += 256) edges[i] = sorted[lo + i];
    __syncthreads();
    for (int i = tid; i < ne; i += 256)
        atomicAdd(&cnt[((unsigned)edges[i]) >> 17], 1);
    __syncthreads();
    // pair-scan of 512 counts with 256 threads
    int c0 = cnt[2 * tid], c1 = cnt[2 * tid + 1];
    ps[tid] = c0 + c1;
    __syncthreads();
#pragma unroll
    for (int off = 1; off < 256; off <<= 1) {
        int t = (tid >= off) ? ps[tid - off] : 0;
        __syncthreads();
        ps[tid] += t;
        __syncthreads();
    }
    int pex = ps[tid] - (c0 + c1);
    excl[2 * tid] = pex;
    excl[2 * tid + 1] = pex + c0;
    __syncthreads();
#pragma unroll
    for (int k = 0; k < 2; k++) {
        int li = tid + k * 256;
        int node = node0 + li;
        if (node < N_NODES) {
            // segment start shifted by li to make room for earlier nodes' self entries
            int st = lo + excl[li] + li;
            int c = cnt[li];
            rs2[node] = make_int2(st, st + c + 1);      // +1: self entry included
            dis[node] = rsqrtf((float)c + 1.0f);
            csr_src[st + c] = node;                     // self-loop entry (global id)
        }
    }
    // reuse cnt as fill cursors
    cnt[tid] = 0; cnt[tid + 256] = 0;
    __syncthreads();
    for (int i = tid; i < ne; i += 256) {
        int v = edges[i];
        int li = ((unsigned)v) >> 17;
        int idx = atomicAdd(&cnt[li], 1);
        csr_src[lo + excl[li] + li + idx] = v & 0x1FFFF;
    }
}

// ---------------- MFMA GEMM: C_fp8[r][c] = e4m3( (sum_k A[r][k] W[k][c]) * scale[r] )
template<bool A_FP32>
__global__ __launch_bounds__(256) void gemm_mfma_kernel(const void* __restrict__ Av,
                                                        const __hip_bfloat16* __restrict__ Wt,
                                                        const float* __restrict__ scale,
                                                        unsigned char* __restrict__ C, int nrows) {
    __shared__ float Cs[64 * 132];
    int tid = threadIdx.x;
    int wave = tid >> 6, lane = tid & 63;
    int quad = lane >> 4, l16 = lane & 15;
    int row0 = blockIdx.x * 64;
    int arow = row0 + wave * 16 + l16;
    int arow_c = min(arow, nrows - 1);

    const __hip_bfloat16* A16 = (const __hip_bfloat16*)Av;
    const float* A32 = (const float*)Av;

    f32x4 acc[8];
#pragma unroll
    for (int t = 0; t < 8; t++) acc[t] = (f32x4){0.f, 0.f, 0.f, 0.f};

#pragma unroll
    for (int kt = 0; kt < 4; kt++) {
        int kbase = kt * 32 + quad * 8;
        union { bf16x8 v; __hip_bfloat16 h[8]; uint4 u; } au;
        if (A_FP32) {
            const float* ap = A32 + (size_t)arow_c * 128 + kbase;
            float4 u0 = *(const float4*)ap;
            float4 u1 = *(const float4*)(ap + 4);
            au.h[0] = __float2bfloat16(u0.x); au.h[1] = __float2bfloat16(u0.y);
            au.h[2] = __float2bfloat16(u0.z); au.h[3] = __float2bfloat16(u0.w);
            au.h[4] = __float2bfloat16(u1.x); au.h[5] = __float2bfloat16(u1.y);
            au.h[6] = __float2bfloat16(u1.z); au.h[7] = __float2bfloat16(u1.w);
        } else {
            au.u = *(const uint4*)(A16 + (size_t)arow_c * 128 + kbase);
        }
#pragma unroll
        for (int t = 0; t < 8; t++) {
            bf16x8 b = *(const bf16x8*)(Wt + (size_t)(t * 16 + l16) * 128 + kbase);
            acc[t] = __builtin_amdgcn_mfma_f32_16x16x32_bf16(au.v, b, acc[t], 0, 0, 0);
        }
    }

    int rbase = wave * 16 + quad * 4;
    float s[4];
#pragma unroll
    for (int r = 0; r < 4; r++) s[r] = scale[min(row0 + rbase + r, nrows - 1)];
#pragma unroll
    for (int t = 0; t < 8; t++) {
#pragma unroll
        for (int r = 0; r < 4; r++)
            Cs[(rbase + r) * 132 + t * 16 + l16] = acc[t][r] * s[r];
    }
    __syncthreads();

#pragma unroll
    for (int p = 0; p < 4; p++) {
        int g = p * 256 + tid;
        int row = g >> 4, c8 = (g & 15) * 8;
        int grow = row0 + row;
        if (grow < nrows) {
            const float* cp = &Cs[row * 132 + c8];
            float4 v0 = *(const float4*)cp;
            float4 v1 = *(const float4*)(cp + 4);
            int w0 = __builtin_amdgcn_cvt_pk_fp8_f32(v0.x, v0.y, 0, false);
            w0 = __builtin_amdgcn_cvt_pk_fp8_f32(v0.z, v0.w, w0, true);
            int w1 = __builtin_amdgcn_cvt_pk_fp8_f32(v1.x, v1.y, 0, false);
            w1 = __builtin_amdgcn_cvt_pk_fp8_f32(v1.z, v1.w, w1, true);
            *(uint2*)(C + (size_t)grow * 128 + c8) = make_uint2((unsigned)w0, (unsigned)w1);
        }
    }
}

// ---------------- GCN aggregation: 2 nodes/wave, uint2 gathers, 8 gathers/round,
// masked single-round tail, 32-bit addressing.
// FUSE_POOL: NO ATOMICS in common path — per-wave shfl combine -> plain LDS writes ->
// one non-atomic 512B block-partial store to pp[blockIdx]. Boundary blocks (rare) use
// per-node atomics into tiny psum0[64][128]. pool_reduce + mlp reduce pp + psum0. ----------------
__device__ __forceinline__ void accum8p(f32x2* acc, uint2 u) {
    acc[0] += __builtin_amdgcn_cvt_pk_f32_fp8((int)u.x, false);
    acc[1] += __builtin_amdgcn_cvt_pk_f32_fp8((int)u.x, true);
    acc[2] += __builtin_amdgcn_cvt_pk_f32_fp8((int)u.y, false);
    acc[3] += __builtin_amdgcn_cvt_pk_f32_fp8((int)u.y, true);
}

template<bool FUSE_POOL>
__global__ __launch_bounds__(256, 8) void agg_kernel(const unsigned char* __restrict__ h8,
                                                     const float* __restrict__ dis,
                                                     const int2* __restrict__ rs2,
                                                     const int* __restrict__ csr_src,
                                                     const float* __restrict__ bias,
                                                     __hip_bfloat16* __restrict__ out,
                                                     const int* __restrict__ batch,
                                                     float* __restrict__ pp,
                                                     float* __restrict__ psum0, int n) {
    __shared__ float psum_s[512];          // 4 waves x 128 feats (FUSE_POOL only)
    int tid = threadIdx.x;
    int wid = tid >> 6;
    int lane = tid & 63;
    int half = lane >> 5;          // 0: node A, 1: node B
    int q = lane >> 4;             // quarter 0..3
    int f = lane & 15;
    int l32 = lane & 31;
    int sub = q & 1;               // which of the 2 edges in this gather slot
    int hb = half << 5;            // shfl base for this half's csr chunk
    unsigned fo = (unsigned)(f * 8);
    int blk0 = (int)blockIdx.x * 8;          // first node of this block

    if (FUSE_POOL) {
        psum_s[tid] = 0.f; psum_s[tid + 256] = 0.f;
        __syncthreads();
    }

    int nodeA = blk0 + wid * 2;
    bool active = nodeA < n;       // grid is exactly full at n=100000; guard kept for safety
    if (!FUSE_POOL && !active) return;
    int nodeB = nodeA + 1;
    bool hasB = nodeB < n;
    int myNode = half ? (hasB ? nodeB : nodeA) : nodeA;
    myNode = min(myNode, n - 1);

    int2 se = rs2[myNode];
    int i0 = se.x;
    int deg = se.y - se.x;         // includes self entry (>= 1)
    if ((half && !hasB) || !active) deg = 0;
    float dn = dis[myNode];

    f32x2 acc[4];
#pragma unroll
    for (int j = 0; j < 4; j++) acc[j] = (f32x2){0.f, 0.f};

    for (int base = 0; base < deg; base += 32) {
        int cnt = min(deg - base, 32);              // uniform within half
        int idx = csr_src[i0 + base + min(l32, cnt - 1)];
        int e = 0;
        // main: 16 edges per half per round, 8 independent uint2 gathers in flight
        for (; e + 16 <= cnt; e += 16) {
            int s0 = __shfl(idx, hb + e + sub, 64);
            int s1 = __shfl(idx, hb + e + 2 + sub, 64);
            int s2 = __shfl(idx, hb + e + 4 + sub, 64);
            int s3 = __shfl(idx, hb + e + 6 + sub, 64);
            int s4 = __shfl(idx, hb + e + 8 + sub, 64);
            int s5 = __shfl(idx, hb + e + 10 + sub, 64);
            int s6 = __shfl(idx, hb + e + 12 + sub, 64);
            int s7 = __shfl(idx, hb + e + 14 + sub, 64);
            uint2 u0 = *(const uint2*)(h8 + (unsigned)(s0 << 7) + fo);
            uint2 u1 = *(const uint2*)(h8 + (unsigned)(s1 << 7) + fo);
            uint2 u2 = *(const uint2*)(h8 + (unsigned)(s2 << 7) + fo);
            uint2 u3 = *(const uint2*)(h8 + (unsigned)(s3 << 7) + fo);
            uint2 u4 = *(const uint2*)(h8 + (unsigned)(s4 << 7) + fo);
            uint2 u5 = *(const uint2*)(h8 + (unsigned)(s5 << 7) + fo);
            uint2 u6 = *(const uint2*)(h8 + (unsigned)(s6 << 7) + fo);
            uint2 u7 = *(const uint2*)(h8 + (unsigned)(s7 << 7) + fo);
            accum8p(acc, u0);
            accum8p(acc, u1);
            accum8p(acc, u2);
            accum8p(acc, u3);
            accum8p(acc, u4);
            accum8p(acc, u5);
            accum8p(acc, u6);
            accum8p(acc, u7);
        }
        // tail: ONE masked round of 8 gathers covering edges e..e+15
        // (clamped index; invalid lanes zero their fp8 payload — 0x00 decodes to 0.0)
        if (e < cnt) {
            int r = cnt - 1;
#pragma unroll
            for (int k = 0; k < 8; k++) {
                int ln = e + 2 * k + sub;
                int s = __shfl(idx, hb + min(ln, r), 64);
                uint2 u = *(const uint2*)(h8 + (unsigned)(s << 7) + fo);
                if (ln > r) { u.x = 0u; u.y = 0u; }
                accum8p(acc, u);
            }
        }
    }

    // combine gather-slot pairs: Q0 += Q1 (node A), Q2 += Q3 (node B)
#pragma unroll
    for (int j = 0; j < 4; j++) {
        f32x2 v = acc[j];
        v[0] += __shfl_down(v[0], 16, 64);
        v[1] += __shfl_down(v[1], 16, 64);
        acc[j] = v;
    }

    bool res = active && (sub == 0) && (half == 0 || hasB);

    if (FUSE_POOL) {
        // per-node ReLU(bias + dn*acc) on q0 (node A) and q2 (node B) lanes
        float rv[8];
        {
            float4 b0 = *(const float4*)(bias + f * 8);
            float4 b1 = *(const float4*)(bias + f * 8 + 4);
            float bb[8] = {b0.x, b0.y, b0.z, b0.w, b1.x, b1.y, b1.z, b1.w};
#pragma unroll
            for (int k = 0; k < 4; k++) {
                rv[2 * k]     = fmaxf(fmaf(acc[k][0], dn, bb[2 * k]), 0.f);
                rv[2 * k + 1] = fmaxf(fmaf(acc[k][1], dn, bb[2 * k + 1]), 0.f);
            }
        }
        int gA = batch[blk0];
        int gB = batch[min(blk0 + 7, n - 1)];
        if (gA == gB) {
            // fold node B (q2 lanes) into node A lanes (q0): graph-sum only needs totals
#pragma unroll
            for (int k = 0; k < 8; k++) rv[k] += __shfl_down(rv[k], 32, 64);
            if (lane < 16 && active) {
#pragma unroll
                for (int k = 0; k < 8; k++) psum_s[wid * 128 + f * 8 + k] = rv[k];
            }
            __syncthreads();
            if (tid < 128) {
                float v = psum_s[tid] + psum_s[128 + tid] + psum_s[256 + tid] + psum_s[384 + tid];
                pp[(size_t)blockIdx.x * 128 + tid] = v;   // non-atomic block partial
            }
        } else {
            // graph boundary inside block (rare): per-node atomics into psum0
            if (res) {
                int g = batch[myNode];
#pragma unroll
                for (int k = 0; k < 8; k++)
                    atomicAdd(&psum0[g * 128 + f * 8 + k], rv[k]);
            }
        }
    } else {
        if (res) {
            float4 b0 = *(const float4*)(bias + f * 8);
            float4 b1 = *(const float4*)(bias + f * 8 + 4);
            float r0 = fmaxf(fmaf(acc[0][0], dn, b0.x), 0.f);
            float r1 = fmaxf(fmaf(acc[0][1], dn, b0.y), 0.f);
            float r2 = fmaxf(fmaf(acc[1][0], dn, b0.z), 0.f);
            float r3 = fmaxf(fmaf(acc[1][1], dn, b0.w), 0.f);
            float r4 = fmaxf(fmaf(acc[2][0], dn, b1.x), 0.f);
            float r5 = fmaxf(fmaf(acc[2][1], dn, b1.y), 0.f);
            float r6 = fmaxf(fmaf(acc[3][0], dn, b1.z), 0.f);
            float r7 = fmaxf(fmaf(acc[3][1], dn, b1.w), 0.f);
            __hip_bfloat162 p0 = __float22bfloat162_rn(make_float2(r0, r1));
            __hip_bfloat162 p1 = __float22bfloat162_rn(make_float2(r2, r3));
            __hip_bfloat162 p2 = __float22bfloat162_rn(make_float2(r4, r5));
            __hip_bfloat162 p3 = __float22bfloat162_rn(make_float2(r6, r7));
            uint4 pk;
            pk.x = *(unsigned int*)&p0; pk.y = *(unsigned int*)&p1;
            pk.z = *(unsigned int*)&p2; pk.w = *(unsigned int*)&p3;
            *(uint4*)(out + (size_t)myNode * 128 + f * 8) = pk;
        }
    }
}

// ---------------- pool partial reduction: 512 blocks (64 graphs x 8 chunks) ----------------
__global__ __launch_bounds__(256) void pool_reduce_kernel(const float* __restrict__ pp,
                                                          const int* __restrict__ gstart,
                                                          float* __restrict__ pp2) {
    __shared__ float red[256];
    int r = blockIdx.x;
    int g = r >> 3, c = r & (RED_CHUNKS - 1);
    int lo = gstart[g], hi = gstart[g + 1];
    int b_lo = (lo + 7) >> 3;
    int b_hi = hi >> 3;                    // exclusive; boundary blocks excluded (go via psum0)
    int nb = b_hi - b_lo;
    int per = (nb + RED_CHUNKS - 1) >> 3;
    int r0 = b_lo + c * per;
    int r1 = min(b_hi, r0 + per);
    int feat = threadIdx.x & 127;
    int sg = threadIdx.x >> 7;             // 2-way row split
    float s = 0.f;
    for (int b = r0 + sg; b < r1; b += 2)
        s += pp[(size_t)b * 128 + feat];
    red[threadIdx.x] = s;
    __syncthreads();
    if (threadIdx.x < 128)
        pp2[(size_t)r * 128 + threadIdx.x] = red[threadIdx.x] + red[threadIdx.x + 128];
}

// ---------------- fused final MLP (reads 8 pp2 rows + psum0 per graph) ----------------
__global__ __launch_bounds__(256) void mlp_kernel(const float* __restrict__ pp2,
                                                  const float* __restrict__ psum0,
                                                  const int* __restrict__ gstart,
                                                  const float* __restrict__ sv,
                                                  const float* __restrict__ act,
                                                  const float* __restrict__ Wf1,
                                                  const float* __restrict__ bf1,
                                                  const float* __restrict__ Wf2,
                                                  const float* __restrict__ bf2,
                                                  const float* __restrict__ Wo,
                                                  const float* __restrict__ bo,
                                                  float* __restrict__ out) {
    int g = blockIdx.x, tid = threadIdx.x;
    __shared__ float z[224];
    __shared__ float z1[256];
    __shared__ float red[256];
    int lo = gstart[g], hi = gstart[g + 1];
    if (tid < 128) {
        float s = psum0[g * 128 + tid];
#pragma unroll
        for (int c = 0; c < RED_CHUNKS; c++)
            s += pp2[(size_t)(g * RED_CHUNKS + c) * 128 + tid];
        float cnt = fmaxf((float)(hi - lo), 1.f);
        z[tid] = s / cnt;
    } else if (tid < 192) {
        z[tid] = sv[g * 64 + (tid - 128)];
    } else if (tid < 224) {
        z[tid] = act[g * 32 + (tid - 192)];
    }
    __syncthreads();
    float a = bf1[tid];
    for (int k = 0; k < 224; k++) a = fmaf(z[k], Wf1[k * 256 + tid], a);
    z1[tid] = fmaxf(a, 0.f);
    __syncthreads();
    float b = bf2[tid];
    for (int k = 0; k < 256; k++) b = fmaf(z1[k], Wf2[k * 256 + tid], b);
    b = fmaxf(b, 0.f);
    red[tid] = b * Wo[tid];
    __syncthreads();
    for (int off = 128; off > 0; off >>= 1) {
        if (tid < off) red[tid] += red[tid + off];
        __syncthreads();
    }
    if (tid == 0) out[g] = red[0] + bo[0];
}

// ---------------- launch ----------------
extern "C" void kernel_launch(void* const* d_in, const int* in_sizes, int n_in,
                              void* d_out, int out_size, void* d_ws, size_t ws_size,
                              hipStream_t stream) {
    const float* x   = (const float*)d_in[0];
    const int*   eidx = (const int*)d_in[1];
    const int*   batch = (const int*)d_in[2];
    const float* sv  = (const float*)d_in[3];
    const float* act = (const float*)d_in[4];
    const float* W1  = (const float*)d_in[5];
    const float* b1  = (const float*)d_in[6];
    const float* W2  = (const float*)d_in[7];
    const float* b2  = (const float*)d_in[8];
    const float* Wf1 = (const float*)d_in[9];
    const float* bf1 = (const float*)d_in[10];
    const float* Wf2 = (const float*)d_in[11];
    const float* bf2 = (const float*)d_in[12];
    const float* Wo  = (const float*)d_in[13];
    const float* bo  = (const float*)d_in[14];
    float* out = (float*)d_out;

    const int* srcp = eidx;             // edge_index[0]
    const int* dstp = eidx + N_EDGES;   // edge_index[1]

    char* w = (char*)d_ws;
    int* gcur = (int*)w;               w += (size_t)NBUCK * 4;
    int2* rs2 = (int2*)w;              w += (size_t)N_NODES * 8;
    float* dis = (float*)w;            w += (size_t)N_NODES * 4;
    int* gstart = (int*)w;             w += (size_t)(N_GRAPHS + 1) * 4;
    w = (char*)(((uintptr_t)w + 255) & ~(uintptr_t)255);
    float* pp = (float*)w;             w += (size_t)NPB * HDIM * 4;              // 6.4 MB block partials
    float* pp2 = (float*)w;            w += (size_t)N_GRAPHS * RED_CHUNKS * HDIM * 4;  // 256 KB
    float* psum0 = (float*)w;          w += (size_t)N_GRAPHS * HDIM * 4;         // boundary partials
    w = (char*)(((uintptr_t)w + 255) & ~(uintptr_t)255);
    int* csr_src = (int*)w;            w += (size_t)NBUCK * CAP * 4;
    w = (char*)(((uintptr_t)w + 255) & ~(uintptr_t)255);
    int* sorted = (int*)w;             w += (size_t)NBUCK * CAP * 4;
    w = (char*)(((uintptr_t)w + 255) & ~(uintptr_t)255);
    __hip_bfloat16* Wt1 = (__hip_bfloat16*)w;   w += (size_t)HDIM * HDIM * 2;
    __hip_bfloat16* Wt2 = (__hip_bfloat16*)w;   w += (size_t)HDIM * HDIM * 2;
    w = (char*)(((uintptr_t)w + 255) & ~(uintptr_t)255);
    unsigned char* hbuf = (unsigned char*)w;    w += (size_t)N_NODES * HDIM;      // fp8
    w = (char*)(((uintptr_t)w + 255) & ~(uintptr_t)255);
    __hip_bfloat16* abuf = (__hip_bfloat16*)w;  w += (size_t)N_NODES * HDIM * 2;  // bf16

    setup_kernel<<<SETUP_NBLK, 256, 0, stream>>>(batch, gstart, W1, W2, Wt1, Wt2, gcur, psum0);

    scatter_kernel<<<SCAT_NBLK, 256, 0, stream>>>(srcp, dstp, gcur, sorted, N_EDGES);
    bucket_build_kernel<<<NBUCK, 256, 0, stream>>>(sorted, gcur, rs2, dis, csr_src);

    int gemm_blocks = (N_NODES + 63) / 64;

    gemm_mfma_kernel<true><<<gemm_blocks, 256, 0, stream>>>(x, Wt1, dis, hbuf, N_NODES);
    agg_kernel<false><<<NPB, 256, 0, stream>>>(hbuf, dis, rs2, csr_src, b1, abuf,
                                               batch, pp, psum0, N_NODES);
    gemm_mfma_kernel<false><<<gemm_blocks, 256, 0, stream>>>(abuf, Wt2, dis, hbuf, N_NODES);
    // layer-2 agg fuses global_mean_pool numerator: atomic-free block partials
    agg_kernel<true><<<NPB, 256, 0, stream>>>(hbuf, dis, rs2, csr_src, b2, abuf,
                                              batch, pp, psum0, N_NODES);

    pool_reduce_kernel<<<N_GRAPHS * RED_CHUNKS, 256, 0, stream>>>(pp, gstart, pp2);
    mlp_kernel<<<N_GRAPHS, 256, 0, stream>>>(pp2, psum0, gstart, sv, act,
                                             Wf1, bf1, Wf2, bf2, Wo, bo, out);
}